// Round 2
// baseline (1084.813 us; speedup 1.0000x reference)
//
#include <hip/hip_runtime.h>
#include <stdint.h>
#include <stddef.h>

// ---------------- problem dims ----------------
#define BATCH   4
#define SEQLEN  2048
#define HM      1024
#define DINNER  2048
#define NH      8
#define HD      256
#define NS      64
#define CONVD   2176
#define DCONV   16
#define DPROJ   4232
#define LDZX    4352            // padded D_IN_PROJ (34*128)
#define ROWS    (BATCH*SEQLEN)  // 8192
#define QC      256             // scan chunk length
#define NC      (SEQLEN/QC)     // 8 chunks

typedef __attribute__((ext_vector_type(8))) short short8;
typedef __attribute__((ext_vector_type(4))) short short4v;
typedef __attribute__((ext_vector_type(4))) float f32x4;

// ---------------- workspace layout (bytes), peak 156,241,920 (~149 MiB) ----
// winT  bf16[4352][1024]   8,912,896
// woutT bf16[1024][2048]   4,194,304
// wnlT  bf16[1024][1024]   2,097,152
// dt,dA f32 [8192][8]        262,144 x2
// P     f32 [256]              4,096 (padded)
// xbf   bf16[8192][1024]  16,777,216  (also S f32[256][16384], also tb bf16[8192][1024])
// zxb   bf16[8192][4352]  71,303,168  (z cols 0..2047, xBC-pre cols 2048..4223)
// xbc   bf16[8192][2176]  35,651,584  (post conv+silu; also yn bf16[8192][2048])
// Hg    f32 [256][16384]  16,777,216
// yfull bf16[8192][2048] = d_out (33,554,432 B exactly)
static constexpr size_t O_WIN  = 0;
static constexpr size_t O_WOUT = O_WIN  + 8912896ull;
static constexpr size_t O_WNL  = O_WOUT + 4194304ull;
static constexpr size_t O_DT   = O_WNL  + 2097152ull;
static constexpr size_t O_DA   = O_DT   + 262144ull;
static constexpr size_t O_P    = O_DA   + 262144ull;
static constexpr size_t O_XBF  = O_P    + 4096ull;
static constexpr size_t O_ZXB  = O_XBF  + 16777216ull;
static constexpr size_t O_XBC  = O_ZXB  + 71303168ull;
static constexpr size_t O_HG   = O_XBC  + 35651584ull;
static constexpr size_t O_END  = O_HG   + 16777216ull;  // 156,241,920
static constexpr size_t O_S    = O_XBF;  // scan S reuses xbf region (dead after GEMM1)
static constexpr size_t O_TB   = O_XBF;  // tb reuses same region (dead after scan)
static constexpr size_t O_YN   = O_XBC;  // yn reuses xbc region (dead after scan)

// ---------------- helpers ----------------
__device__ __forceinline__ short f2bf(float f) {
  union { float f; uint32_t u; } v; v.f = f;
  uint32_t r = v.u + 0x7fffu + ((v.u >> 16) & 1u);
  return (short)(r >> 16);
}

__device__ __forceinline__ float bf2f(short s) {
  union { float f; uint32_t u; } v;
  v.u = ((uint32_t)(uint16_t)s) << 16;
  return v.f;
}

__device__ __forceinline__ void gload_lds16(const void* g, void* l) {
  __builtin_amdgcn_global_load_lds(
      (const __attribute__((address_space(1))) uint32_t*)g,
      (__attribute__((address_space(3))) uint32_t*)l, 16, 0, 0);
}

__device__ __forceinline__ float sigmoidf_fast(float x) {
  return 1.f / (1.f + __expf(-x));
}

// ---------------- cast kernels ----------------
__global__ __launch_bounds__(256) void cast_x_kernel(const float* __restrict__ x,
                                                     short* __restrict__ xb) {
  int i = blockIdx.x * 256 + threadIdx.x;  // float4 index, 2097152 total
  f32x4 v = ((const f32x4*)x)[i];
  short4v o = { f2bf(v[0]), f2bf(v[1]), f2bf(v[2]), f2bf(v[3]) };
  ((short4v*)xb)[i] = o;
}

__global__ __launch_bounds__(256) void cast_winT_kernel(const float* __restrict__ W,
                                                        short* __restrict__ Wt) {
  int i = blockIdx.x * 256 + threadIdx.x;  // over 4352*1024 ; Wt[n][k]
  int n = i >> 10, k = i & 1023;
  float v = (n < DPROJ) ? W[(size_t)k * DPROJ + n] : 0.f;
  Wt[i] = f2bf(v);
}

__global__ __launch_bounds__(256) void cast_woutT_kernel(const float* __restrict__ W,
                                                         short* __restrict__ Wt) {
  int i = blockIdx.x * 256 + threadIdx.x;  // over 1024*2048 ; Wt[n][k], k in 2048
  int n = i >> 11, k = i & 2047;
  Wt[i] = f2bf(W[(size_t)k * HM + n]);
}

__global__ __launch_bounds__(256) void cast_wnlT_kernel(const float* __restrict__ W,
                                                        short* __restrict__ Wt) {
  int i = blockIdx.x * 256 + threadIdx.x;  // over 1024*1024
  int n = i >> 10, k = i & 1023;
  Wt[i] = f2bf(W[(size_t)k * HM + n]);
}

// ---------------- dt in f32 (exp-amplified path, exact) ----------------
__global__ __launch_bounds__(256) void dt_kernel(const float* __restrict__ x,
                                                 const float* __restrict__ W_in,
                                                 const float* __restrict__ dt_bias,
                                                 const float* __restrict__ A_log,
                                                 float* __restrict__ dtg,
                                                 float* __restrict__ dag) {
  int row = blockIdx.x, tid = threadIdx.x;
  float p[NH];
#pragma unroll
  for (int h = 0; h < NH; ++h) p[h] = 0.f;
  for (int k = tid; k < HM; k += 256) {
    float xv = x[(size_t)row * HM + k];
    const float* w = &W_in[(size_t)k * DPROJ + (DPROJ - NH)];
#pragma unroll
    for (int h = 0; h < NH; ++h) p[h] = fmaf(xv, w[h], p[h]);
  }
#pragma unroll
  for (int h = 0; h < NH; ++h)
#pragma unroll
    for (int o = 32; o; o >>= 1) p[h] += __shfl_down(p[h], o);
  __shared__ float red[4][NH];
  int lane = tid & 63, w4 = tid >> 6;
  if (lane == 0)
#pragma unroll
    for (int h = 0; h < NH; ++h) red[w4][h] = p[h];
  __syncthreads();
  if (tid < NH) {
    float s = red[0][tid] + red[1][tid] + red[2][tid] + red[3][tid] + dt_bias[tid];
    float dtv = (s > 20.f) ? s : log1pf(expf(s));
    float A = -expf(A_log[tid]);
    dtg[row * NH + tid] = dtv;
    dag[row * NH + tid] = expf(dtv * A);
  }
}

// ---------------- bf16 MFMA GEMM, 128x128 tile, BK=64 ----------------
// A [M][K] bf16 row-major, B [N][K] bf16 row-major (i.e. B^T of math B)
// EPI 1: t=y*rsqrt(1+y^2) -> bf16   EPI 2: y+bias[col]+resid -> f32   EPI 3: bf16
template <int EPI>
__global__ __launch_bounds__(256)
void gemm_bf16(const short* __restrict__ A, const short* __restrict__ B,
               int K, int nTilesN, int N_out,
               float* __restrict__ Cf, short* __restrict__ Cb,
               const float* __restrict__ bias, const float* __restrict__ resid) {
  __shared__ alignas(16) char lds[32768];
  char* As = lds;
  char* Bs = lds + 16384;
  const int tid = threadIdx.x;
  const int bid = blockIdx.x;
  const int m0 = (bid / nTilesN) * 128;
  const int n0 = (bid % nTilesN) * 128;
  const int lane = tid & 63;
  const int wave = tid >> 6;
  const int wr = wave >> 1, wc = wave & 1;  // 2x2 waves, 64x64 each
  const int lrow = lane & 15, lk = lane >> 4;

  f32x4 acc[4][4];
#pragma unroll
  for (int i = 0; i < 4; ++i)
#pragma unroll
    for (int j = 0; j < 4; ++j) acc[i][j] = (f32x4)0.f;

  for (int k0 = 0; k0 < K; k0 += 64) {
    // stage A,B tiles: 128 rows x 128 bytes, XOR-swizzled source (rule #21)
#pragma unroll
    for (int r = 0; r < 4; ++r) {
      int p = r * 4096 + tid * 16;
      int row = p >> 7, c = p & 127;
      int sc = c ^ ((row & 7) << 4);
      gload_lds16((const char*)A + ((size_t)(m0 + row) * K + k0) * 2 + sc, As + p);
      gload_lds16((const char*)B + ((size_t)(n0 + row) * K + k0) * 2 + sc, Bs + p);
    }
    asm volatile("s_waitcnt vmcnt(0)" ::: "memory");
    __syncthreads();
#pragma unroll
    for (int ks = 0; ks < 2; ++ks) {
      short8 av[4], bv[4];
#pragma unroll
      for (int i = 0; i < 4; ++i) {
        int arow = wr * 64 + i * 16 + lrow;
        av[i] = *(const short8*)(As + arow * 128 + ((ks * 64 + lk * 16) ^ ((arow & 7) << 4)));
        int brow = wc * 64 + i * 16 + lrow;
        bv[i] = *(const short8*)(Bs + brow * 128 + ((ks * 64 + lk * 16) ^ ((brow & 7) << 4)));
      }
#pragma unroll
      for (int i = 0; i < 4; ++i)
#pragma unroll
        for (int j = 0; j < 4; ++j)
          acc[i][j] = __builtin_amdgcn_mfma_f32_16x16x32_bf16(av[i], bv[j], acc[i][j], 0, 0, 0);
    }
    __syncthreads();
  }

  const int row0 = m0 + wr * 64, col0 = n0 + wc * 64;
#pragma unroll
  for (int i = 0; i < 4; ++i)
#pragma unroll
    for (int j = 0; j < 4; ++j)
#pragma unroll
      for (int r = 0; r < 4; ++r) {
        int row = row0 + i * 16 + lk * 4 + r;
        int col = col0 + j * 16 + lrow;
        float v = acc[i][j][r];
        if (EPI == 1) {
          float t = v * rsqrtf(1.f + v * v);
          Cb[(size_t)row * N_out + col] = f2bf(t);
        } else if (EPI == 2) {
          Cf[(size_t)row * N_out + col] = v + bias[col] + resid[(size_t)row * N_out + col];
        } else {
          Cb[(size_t)row * N_out + col] = f2bf(v);
        }
      }
}

// ---------------- depthwise causal conv16 + SiLU (bf16 in/out) ----------------
__global__ __launch_bounds__(256) void conv_silu_kernel(const short* __restrict__ zxb,
                                                        const float* __restrict__ cw,
                                                        const float* __restrict__ cbias,
                                                        short* __restrict__ xbc) {
  int i = blockIdx.x * 256 + threadIdx.x;
  if (i >= ROWS * CONVD) return;
  int c = i % CONVD;
  int row = i / CONVD;
  int t = row & (SEQLEN - 1);
  float acc = cbias[c];
  const float* wp = cw + c * DCONV;
  const short* ip = zxb + (size_t)row * LDZX + DINNER + c;
#pragma unroll
  for (int k = 0; k < DCONV; ++k) {
    int tt = t - (DCONV - 1) + k;
    if (tt >= 0) acc = fmaf(bf2f(ip[(ptrdiff_t)(k - (DCONV - 1)) * LDZX]), wp[k], acc);
  }
  xbc[i] = f2bf(acc * sigmoidf_fast(acc));
}

// ---------------- scan pass A: per-chunk state contribution ----------------
// S_c[p][n] = sum_t w_t dt_t x_t[p] B_t[n],  w_t = prod_{r>t} dA_r ; P_c = prod dA
__global__ __launch_bounds__(256)
void scan_passA(const short* __restrict__ xbc, const float* __restrict__ dtg,
                const float* __restrict__ dag, float* __restrict__ Sg,
                float* __restrict__ Pg) {
  __shared__ alignas(16) float Bl[QC][NS];
  __shared__ float wdt[QC], dAl[QC], dtl[QC];
  int blk = blockIdx.x;  // bh*NC + c
  int c = blk & (NC - 1);
  int bh = blk >> 3;
  int h = bh & (NH - 1);
  int b = bh >> 3;
  int tid = threadIdx.x;
  int rowbase = b * SEQLEN + c * QC;
  for (int j = tid; j < QC * NS; j += 256) {
    int tl = j >> 6, n = j & 63;
    Bl[tl][n] = bf2f(xbc[(size_t)(rowbase + tl) * CONVD + DINNER + n]);
  }
  dAl[tid] = dag[(rowbase + tid) * NH + h];
  dtl[tid] = dtg[(rowbase + tid) * NH + h];
  __syncthreads();
  if (tid == 0) {
    float w = 1.f;
    for (int tl = QC - 1; tl >= 0; --tl) {
      wdt[tl] = w * dtl[tl];
      w *= dAl[tl];
    }
    Pg[blk] = w;
  }
  __syncthreads();
  float S[NS];
#pragma unroll
  for (int n = 0; n < NS; ++n) S[n] = 0.f;
  const short* xp = xbc + (size_t)rowbase * CONVD + h * HD + tid;
  float xnext = bf2f(xp[0]);
  for (int tl = 0; tl < QC; ++tl) {
    float xv = xnext;
    if (tl < QC - 1) xnext = bf2f(xp[(size_t)(tl + 1) * CONVD]);
    float s = wdt[tl] * xv;
    const f32x4* bb = (const f32x4*)(&Bl[tl][0]);
#pragma unroll
    for (int n4 = 0; n4 < 16; ++n4) {
      f32x4 b4 = bb[n4];
      S[n4 * 4 + 0] = fmaf(s, b4[0], S[n4 * 4 + 0]);
      S[n4 * 4 + 1] = fmaf(s, b4[1], S[n4 * 4 + 1]);
      S[n4 * 4 + 2] = fmaf(s, b4[2], S[n4 * 4 + 2]);
      S[n4 * 4 + 3] = fmaf(s, b4[3], S[n4 * 4 + 3]);
    }
  }
  float* dst = Sg + ((size_t)blk * 256 + tid) * 64;
#pragma unroll
  for (int n4 = 0; n4 < 16; ++n4) {
    f32x4 v = { S[n4 * 4], S[n4 * 4 + 1], S[n4 * 4 + 2], S[n4 * 4 + 3] };
    ((f32x4*)dst)[n4] = v;
  }
}

// ---------------- scan pass B: inter-chunk combine ----------------
__global__ __launch_bounds__(256)
void scan_passB(const float* __restrict__ Sg, const float* __restrict__ Pg,
                const float* __restrict__ init, float* __restrict__ Hg) {
  int blk = blockIdx.x;  // bh*16 + ptile
  int ptile = blk & 15, bh = blk >> 4;
  int h = bh & (NH - 1);
  int tid = threadIdx.x;
  size_t off = (size_t)ptile * 1024 + tid * 4;  // within 16384-elem state
  f32x4 hc = *(const f32x4*)(init + (size_t)h * HD * NS + off);
#pragma unroll 1
  for (int c = 0; c < NC; ++c) {
    *(f32x4*)(Hg + (size_t)(bh * NC + c) * 16384 + off) = hc;
    float P = Pg[bh * NC + c];
    f32x4 s = *(const f32x4*)(Sg + (size_t)(bh * NC + c) * 16384 + off);
    hc = P * hc + s;
  }
}

// ---------------- scan pass C: within-chunk recurrence + outputs ----------------
__global__ __launch_bounds__(256)
void scan_passC(const short* __restrict__ xbc, const float* __restrict__ dtg,
                const float* __restrict__ dag, const float* __restrict__ Hg,
                const float* __restrict__ Dp, short* __restrict__ yfull) {
  __shared__ alignas(16) float Bl[QC][NS];
  __shared__ alignas(16) float Cl[QC][NS];
  __shared__ float dAl[QC], dtl[QC];
  int blk = blockIdx.x;
  int c = blk & (NC - 1), bh = blk >> 3, h = bh & (NH - 1), b = bh >> 3;
  int tid = threadIdx.x;
  int rowbase = b * SEQLEN + c * QC;
  for (int j = tid; j < QC * NS; j += 256) {
    int tl = j >> 6, n = j & 63;
    const short* src = xbc + (size_t)(rowbase + tl) * CONVD + DINNER;
    Bl[tl][n] = bf2f(src[n]);
    Cl[tl][n] = bf2f(src[NS + n]);
  }
  dAl[tid] = dag[(rowbase + tid) * NH + h];
  dtl[tid] = dtg[(rowbase + tid) * NH + h];
  __syncthreads();
  float hst[NS];
  const float* hp = Hg + (size_t)blk * 16384 + tid * 64;
#pragma unroll
  for (int n4 = 0; n4 < 16; ++n4) {
    f32x4 v = ((const f32x4*)hp)[n4];
    hst[n4 * 4] = v[0]; hst[n4 * 4 + 1] = v[1];
    hst[n4 * 4 + 2] = v[2]; hst[n4 * 4 + 3] = v[3];
  }
  float Dh = Dp[h];
  const short* xp = xbc + (size_t)rowbase * CONVD + h * HD + tid;
  short* yp = yfull + (size_t)rowbase * DINNER + h * HD + tid;
  float xnext = bf2f(xp[0]);
  for (int tl = 0; tl < QC; ++tl) {
    float xv = xnext;
    if (tl < QC - 1) xnext = bf2f(xp[(size_t)(tl + 1) * CONVD]);
    float dAt = dAl[tl];
    float s = dtl[tl] * xv;
    const f32x4* bb = (const f32x4*)(&Bl[tl][0]);
    const f32x4* cc = (const f32x4*)(&Cl[tl][0]);
    float y0 = 0.f, y1 = 0.f, y2 = 0.f, y3 = 0.f;
#pragma unroll
    for (int n4 = 0; n4 < 16; ++n4) {
      f32x4 b4 = bb[n4], c4 = cc[n4];
      float h0 = fmaf(hst[n4 * 4 + 0], dAt, s * b4[0]); hst[n4 * 4 + 0] = h0; y0 = fmaf(h0, c4[0], y0);
      float h1 = fmaf(hst[n4 * 4 + 1], dAt, s * b4[1]); hst[n4 * 4 + 1] = h1; y1 = fmaf(h1, c4[1], y1);
      float h2 = fmaf(hst[n4 * 4 + 2], dAt, s * b4[2]); hst[n4 * 4 + 2] = h2; y2 = fmaf(h2, c4[2], y2);
      float h3 = fmaf(hst[n4 * 4 + 3], dAt, s * b4[3]); hst[n4 * 4 + 3] = h3; y3 = fmaf(h3, c4[3], y3);
    }
    yp[(size_t)tl * DINNER] = f2bf((y0 + y1) + (y2 + y3) + Dh * xv);
  }
}

// ---------------- gate (silu(z)) + RMSNorm -> bf16 ----------------
__global__ __launch_bounds__(256)
void gate_norm_kernel(const short* __restrict__ yfull, const short* __restrict__ zxb,
                      const float* __restrict__ norm_w, short* __restrict__ yn) {
  int row = blockIdx.x, tid = threadIdx.x;
  size_t yb = (size_t)row * DINNER, zb = (size_t)row * LDZX;
  float v[8];
  float ss = 0.f;
#pragma unroll
  for (int g = 0; g < 2; ++g) {
    int cidx = g * 1024 + tid * 4;
    short4v y4 = *(const short4v*)(yfull + yb + cidx);
    short4v z4 = *(const short4v*)(zxb + zb + cidx);
#pragma unroll
    for (int j = 0; j < 4; ++j) {
      float z = bf2f(z4[j]);
      float val = bf2f(y4[j]) * z * sigmoidf_fast(z);
      v[g * 4 + j] = val;
      ss = fmaf(val, val, ss);
    }
  }
#pragma unroll
  for (int o = 32; o; o >>= 1) ss += __shfl_down(ss, o);
  __shared__ float red[4];
  if ((tid & 63) == 0) red[tid >> 6] = ss;
  __syncthreads();
  float tot = red[0] + red[1] + red[2] + red[3];
  float scale = rsqrtf(tot * (1.f / (float)DINNER) + 1e-5f);
#pragma unroll
  for (int g = 0; g < 2; ++g) {
    int cidx = g * 1024 + tid * 4;
    short4v o4;
#pragma unroll
    for (int j = 0; j < 4; ++j) o4[j] = f2bf(v[g * 4 + j] * scale * norm_w[cidx + j]);
    *(short4v*)(yn + yb + cidx) = o4;
  }
}

// ---------------- launcher ----------------
extern "C" void kernel_launch(void* const* d_in, const int* in_sizes, int n_in,
                              void* d_out, int out_size, void* d_ws, size_t ws_size,
                              hipStream_t stream) {
  (void)in_sizes; (void)n_in; (void)out_size; (void)ws_size;
  const float* x     = (const float*)d_in[0];
  const float* W_in  = (const float*)d_in[1];
  const float* convw = (const float*)d_in[2];
  const float* convb = (const float*)d_in[3];
  const float* dtb   = (const float*)d_in[4];
  const float* Alog  = (const float*)d_in[5];
  const float* Dp    = (const float*)d_in[6];
  const float* inis  = (const float*)d_in[7];
  const float* nw    = (const float*)d_in[8];
  const float* W_out = (const float*)d_in[9];
  const float* W_nl  = (const float*)d_in[10];
  const float* b_nl  = (const float*)d_in[11];
  float* out = (float*)d_out;
  char* ws = (char*)d_ws;

  short* winT  = (short*)(ws + O_WIN);
  short* woutT = (short*)(ws + O_WOUT);
  short* wnlT  = (short*)(ws + O_WNL);
  float* dtg   = (float*)(ws + O_DT);
  float* dag   = (float*)(ws + O_DA);
  float* Pg    = (float*)(ws + O_P);
  short* xbf   = (short*)(ws + O_XBF);
  short* zxb   = (short*)(ws + O_ZXB);
  short* xbc   = (short*)(ws + O_XBC);
  float* Hg    = (float*)(ws + O_HG);
  float* Sg    = (float*)(ws + O_S);
  short* tb    = (short*)(ws + O_TB);
  short* yn    = (short*)(ws + O_YN);
  short* yfull = (short*)d_out;  // 8192*2048 bf16 == out_size*4 bytes exactly

  cast_x_kernel<<<8192, 256, 0, stream>>>(x, xbf);
  cast_winT_kernel<<<(4352 * 1024) / 256, 256, 0, stream>>>(W_in, winT);
  cast_woutT_kernel<<<(1024 * 2048) / 256, 256, 0, stream>>>(W_out, woutT);
  cast_wnlT_kernel<<<(1024 * 1024) / 256, 256, 0, stream>>>(W_nl, wnlT);
  dt_kernel<<<ROWS, 256, 0, stream>>>(x, W_in, dtb, Alog, dtg, dag);

  gemm_bf16<3><<<64 * 34, 256, 0, stream>>>(xbf, winT, HM, 34, LDZX, nullptr, zxb, nullptr, nullptr);
  conv_silu_kernel<<<(ROWS * CONVD) / 256, 256, 0, stream>>>(zxb, convw, convb, xbc);

  scan_passA<<<32 * NC, 256, 0, stream>>>(xbc, dtg, dag, Sg, Pg);
  scan_passB<<<32 * 16, 256, 0, stream>>>(Sg, Pg, inis, Hg);
  scan_passC<<<32 * NC, 256, 0, stream>>>(xbc, dtg, dag, Hg, Dp, yfull);

  gate_norm_kernel<<<ROWS, 256, 0, stream>>>(yfull, zxb, nw, yn);
  gemm_bf16<1><<<64 * 8, 256, 0, stream>>>(yn, woutT, DINNER, 8, HM, nullptr, tb, nullptr, nullptr);
  gemm_bf16<2><<<64 * 8, 256, 0, stream>>>(tb, wnlT, HM, 8, HM, out, nullptr, b_nl, x);
}

// Round 3
// 535.625 us; speedup vs baseline: 2.0253x; 2.0253x over previous
//
#include <hip/hip_runtime.h>
#include <stdint.h>
#include <stddef.h>

// ---------------- problem dims ----------------
#define BATCH   4
#define SEQLEN  2048
#define HM      1024
#define DINNER  2048
#define NH      8
#define HD      256
#define NS      64
#define CONVD   2176
#define DCONV   16
#define DPROJ   4232
#define LDZX    4352            // padded D_IN_PROJ (34*128)
#define ROWS    (BATCH*SEQLEN)  // 8192
#define QC      256             // scan chunk length
#define NC      (SEQLEN/QC)     // 8 chunks
#define TT      16              // conv timesteps per thread

typedef __attribute__((ext_vector_type(8))) short short8;
typedef __attribute__((ext_vector_type(4))) short short4v;
typedef __attribute__((ext_vector_type(4))) float f32x4;

// ---------------- workspace layout (bytes), peak 156,241,920 (~149 MiB) ----
static constexpr size_t O_WIN  = 0;
static constexpr size_t O_WOUT = O_WIN  + 8912896ull;
static constexpr size_t O_WNL  = O_WOUT + 4194304ull;
static constexpr size_t O_DT   = O_WNL  + 2097152ull;
static constexpr size_t O_DA   = O_DT   + 262144ull;
static constexpr size_t O_P    = O_DA   + 262144ull;
static constexpr size_t O_XBF  = O_P    + 4096ull;
static constexpr size_t O_ZXB  = O_XBF  + 16777216ull;
static constexpr size_t O_XBC  = O_ZXB  + 71303168ull;
static constexpr size_t O_HG   = O_XBC  + 35651584ull;
static constexpr size_t O_END  = O_HG   + 16777216ull;  // 156,241,920
static constexpr size_t O_S    = O_XBF;  // scan S reuses xbf region (dead after GEMM1)
static constexpr size_t O_TB   = O_XBF;  // tb reuses same region (dead after scan)
static constexpr size_t O_YN   = O_XBC;  // yn reuses xbc region (dead after scan)

// ---------------- helpers ----------------
__device__ __forceinline__ short f2bf(float f) {
  union { float f; uint32_t u; } v; v.f = f;
  uint32_t r = v.u + 0x7fffu + ((v.u >> 16) & 1u);
  return (short)(r >> 16);
}

__device__ __forceinline__ float bf2f(short s) {
  union { float f; uint32_t u; } v;
  v.u = ((uint32_t)(uint16_t)s) << 16;
  return v.f;
}

__device__ __forceinline__ void gload_lds16(const void* g, void* l) {
  __builtin_amdgcn_global_load_lds(
      (const __attribute__((address_space(1))) uint32_t*)g,
      (__attribute__((address_space(3))) uint32_t*)l, 16, 0, 0);
}

__device__ __forceinline__ float sigmoidf_fast(float x) {
  return 1.f / (1.f + __expf(-x));
}

// ---------------- cast kernels ----------------
__global__ __launch_bounds__(256) void cast_x_kernel(const float* __restrict__ x,
                                                     short* __restrict__ xb) {
  int i = blockIdx.x * 256 + threadIdx.x;  // float4 index, 2097152 total
  f32x4 v = ((const f32x4*)x)[i];
  short4v o = { f2bf(v[0]), f2bf(v[1]), f2bf(v[2]), f2bf(v[3]) };
  ((short4v*)xb)[i] = o;
}

__global__ __launch_bounds__(256) void cast_winT_kernel(const float* __restrict__ W,
                                                        short* __restrict__ Wt) {
  int i = blockIdx.x * 256 + threadIdx.x;  // over 4352*1024 ; Wt[n][k]
  int n = i >> 10, k = i & 1023;
  float v = (n < DPROJ) ? W[(size_t)k * DPROJ + n] : 0.f;
  Wt[i] = f2bf(v);
}

__global__ __launch_bounds__(256) void cast_woutT_kernel(const float* __restrict__ W,
                                                         short* __restrict__ Wt) {
  int i = blockIdx.x * 256 + threadIdx.x;  // over 1024*2048 ; Wt[n][k], k in 2048
  int n = i >> 11, k = i & 2047;
  Wt[i] = f2bf(W[(size_t)k * HM + n]);
}

__global__ __launch_bounds__(256) void cast_wnlT_kernel(const float* __restrict__ W,
                                                        short* __restrict__ Wt) {
  int i = blockIdx.x * 256 + threadIdx.x;  // over 1024*1024
  int n = i >> 10, k = i & 1023;
  Wt[i] = f2bf(W[(size_t)k * HM + n]);
}

// ---------------- dt in f32 (exp-amplified path, exact) ----------------
__global__ __launch_bounds__(256) void dt_kernel(const float* __restrict__ x,
                                                 const float* __restrict__ W_in,
                                                 const float* __restrict__ dt_bias,
                                                 const float* __restrict__ A_log,
                                                 float* __restrict__ dtg,
                                                 float* __restrict__ dag) {
  int row = blockIdx.x, tid = threadIdx.x;
  float p[NH];
#pragma unroll
  for (int h = 0; h < NH; ++h) p[h] = 0.f;
  for (int k = tid; k < HM; k += 256) {
    float xv = x[(size_t)row * HM + k];
    const float* w = &W_in[(size_t)k * DPROJ + (DPROJ - NH)];
#pragma unroll
    for (int h = 0; h < NH; ++h) p[h] = fmaf(xv, w[h], p[h]);
  }
#pragma unroll
  for (int h = 0; h < NH; ++h)
#pragma unroll
    for (int o = 32; o; o >>= 1) p[h] += __shfl_down(p[h], o);
  __shared__ float red[4][NH];
  int lane = tid & 63, w4 = tid >> 6;
  if (lane == 0)
#pragma unroll
    for (int h = 0; h < NH; ++h) red[w4][h] = p[h];
  __syncthreads();
  if (tid < NH) {
    float s = red[0][tid] + red[1][tid] + red[2][tid] + red[3][tid] + dt_bias[tid];
    float dtv = (s > 20.f) ? s : log1pf(expf(s));
    float A = -expf(A_log[tid]);
    dtg[row * NH + tid] = dtv;
    dag[row * NH + tid] = expf(dtv * A);
  }
}

// ---------------- bf16 MFMA GEMM, 128x128 tile, BK=64 ----------------
// A [M][K] bf16 row-major, B [N][K] bf16 row-major (i.e. B^T of math B)
// EPI 1: t=y*rsqrt(1+y^2) -> bf16   EPI 2: y+bias[col]+resid -> f32   EPI 3: bf16
template <int EPI>
__global__ __launch_bounds__(256)
void gemm_bf16(const short* __restrict__ A, const short* __restrict__ B,
               int K, int nTilesN, int N_out,
               float* __restrict__ Cf, short* __restrict__ Cb,
               const float* __restrict__ bias, const float* __restrict__ resid) {
  __shared__ alignas(16) char lds[32768];
  char* As = lds;
  char* Bs = lds + 16384;
  const int tid = threadIdx.x;
  const int bid = blockIdx.x;
  const int m0 = (bid / nTilesN) * 128;
  const int n0 = (bid % nTilesN) * 128;
  const int lane = tid & 63;
  const int wave = tid >> 6;
  const int wr = wave >> 1, wc = wave & 1;  // 2x2 waves, 64x64 each
  const int lrow = lane & 15, lk = lane >> 4;

  f32x4 acc[4][4];
#pragma unroll
  for (int i = 0; i < 4; ++i)
#pragma unroll
    for (int j = 0; j < 4; ++j) acc[i][j] = (f32x4)0.f;

  for (int k0 = 0; k0 < K; k0 += 64) {
    // stage A,B tiles: 128 rows x 128 bytes, XOR-swizzled source (rule #21)
#pragma unroll
    for (int r = 0; r < 4; ++r) {
      int p = r * 4096 + tid * 16;
      int row = p >> 7, c = p & 127;
      int sc = c ^ ((row & 7) << 4);
      gload_lds16((const char*)A + ((size_t)(m0 + row) * K + k0) * 2 + sc, As + p);
      gload_lds16((const char*)B + ((size_t)(n0 + row) * K + k0) * 2 + sc, Bs + p);
    }
    asm volatile("s_waitcnt vmcnt(0)" ::: "memory");
    __syncthreads();
#pragma unroll
    for (int ks = 0; ks < 2; ++ks) {
      short8 av[4], bv[4];
#pragma unroll
      for (int i = 0; i < 4; ++i) {
        int arow = wr * 64 + i * 16 + lrow;
        av[i] = *(const short8*)(As + arow * 128 + ((ks * 64 + lk * 16) ^ ((arow & 7) << 4)));
        int brow = wc * 64 + i * 16 + lrow;
        bv[i] = *(const short8*)(Bs + brow * 128 + ((ks * 64 + lk * 16) ^ ((brow & 7) << 4)));
      }
#pragma unroll
      for (int i = 0; i < 4; ++i)
#pragma unroll
        for (int j = 0; j < 4; ++j)
          acc[i][j] = __builtin_amdgcn_mfma_f32_16x16x32_bf16(av[i], bv[j], acc[i][j], 0, 0, 0);
    }
    __syncthreads();
  }

  const int row0 = m0 + wr * 64, col0 = n0 + wc * 64;
#pragma unroll
  for (int i = 0; i < 4; ++i)
#pragma unroll
    for (int j = 0; j < 4; ++j)
#pragma unroll
      for (int r = 0; r < 4; ++r) {
        int row = row0 + i * 16 + lk * 4 + r;
        int col = col0 + j * 16 + lrow;
        float v = acc[i][j][r];
        if (EPI == 1) {
          float t = v * rsqrtf(1.f + v * v);
          Cb[(size_t)row * N_out + col] = f2bf(t);
        } else if (EPI == 2) {
          Cf[(size_t)row * N_out + col] = v + bias[col] + resid[(size_t)row * N_out + col];
        } else {
          Cb[(size_t)row * N_out + col] = f2bf(v);
        }
      }
}

// ---------------- depthwise causal conv16 + SiLU, register-blocked ----------
// thread = 2 adjacent channels x TT timesteps; 31-element input halo + 32
// weights in registers; all loads coalesced ushort2 (4B/lane).
__global__ __launch_bounds__(256) void conv_silu_kernel(const short* __restrict__ zxb,
                                                        const float* __restrict__ cw,
                                                        const float* __restrict__ cbias,
                                                        short* __restrict__ xbc) {
  int blk = blockIdx.x;            // 17 * 32 * 4 = 2176 blocks
  int cg = blk % 17;               // channel-pair group (64 pairs each)
  int tg = (blk / 17) % 32;        // time group (4 warps x TT = 64 t)
  int b  = blk / (17 * 32);
  int lane = threadIdx.x & 63;
  int warp = threadIdx.x >> 6;
  int cp = cg * 64 + lane;         // channel pair 0..1087
  int c0 = cp * 2;
  int tbase = (tg * 4 + warp) * TT;

  const short* inp = zxb + (size_t)(b * SEQLEN) * LDZX + DINNER + c0;
  uint32_t in[TT + DCONV - 1];
#pragma unroll
  for (int j = 0; j < TT + DCONV - 1; ++j) {
    int t = tbase + j - (DCONV - 1);
    in[j] = (t >= 0) ? *(const uint32_t*)(inp + (size_t)t * LDZX) : 0u;
  }
  float w0[DCONV], w1[DCONV];
  const float* wp = cw + (size_t)c0 * DCONV;
#pragma unroll
  for (int k = 0; k < DCONV; ++k) { w0[k] = wp[k]; w1[k] = wp[DCONV + k]; }
  float bb0 = cbias[c0], bb1 = cbias[c0 + 1];

  short* outp = xbc + (size_t)(b * SEQLEN) * CONVD + c0;
#pragma unroll
  for (int tt = 0; tt < TT; ++tt) {
    float a0 = bb0, a1 = bb1;
#pragma unroll
    for (int k = 0; k < DCONV; ++k) {
      uint32_t v = in[tt + k];
      a0 = fmaf(bf2f((short)(v & 0xffffu)), w0[k], a0);
      a1 = fmaf(bf2f((short)(v >> 16)), w1[k], a1);
    }
    a0 = a0 * sigmoidf_fast(a0);
    a1 = a1 * sigmoidf_fast(a1);
    uint32_t o = (uint32_t)(uint16_t)f2bf(a0) | ((uint32_t)(uint16_t)f2bf(a1) << 16);
    *(uint32_t*)(outp + (size_t)(tbase + tt) * CONVD) = o;
  }
}

// ---------------- scan pass A: per-chunk state contribution ----------------
// S_c[p][n] = sum_t w_t dt_t x_t[p] B_t[n],  w_t = prod_{r>t} dA_r ; P_c = prod dA
__global__ __launch_bounds__(256)
void scan_passA(const short* __restrict__ xbc, const float* __restrict__ dtg,
                const float* __restrict__ dag, float* __restrict__ Sg,
                float* __restrict__ Pg) {
  __shared__ alignas(16) float Bl[QC][NS];
  __shared__ float wdt[QC], dAl[QC], dtl[QC];
  int blk = blockIdx.x;  // bh*NC + c
  int c = blk & (NC - 1);
  int bh = blk >> 3;
  int h = bh & (NH - 1);
  int b = bh >> 3;
  int tid = threadIdx.x;
  int rowbase = b * SEQLEN + c * QC;
  for (int j = tid; j < QC * NS; j += 256) {
    int tl = j >> 6, n = j & 63;
    Bl[tl][n] = bf2f(xbc[(size_t)(rowbase + tl) * CONVD + DINNER + n]);
  }
  dAl[tid] = dag[(rowbase + tid) * NH + h];
  dtl[tid] = dtg[(rowbase + tid) * NH + h];
  __syncthreads();
  if (tid == 0) {
    float w = 1.f;
    for (int tl = QC - 1; tl >= 0; --tl) {
      wdt[tl] = w * dtl[tl];
      w *= dAl[tl];
    }
    Pg[blk] = w;
  }
  __syncthreads();
  float S[NS];
#pragma unroll
  for (int n = 0; n < NS; ++n) S[n] = 0.f;
  const short* xp = xbc + (size_t)rowbase * CONVD + h * HD + tid;
  float xnext = bf2f(xp[0]);
  for (int tl = 0; tl < QC; ++tl) {
    float xv = xnext;
    if (tl < QC - 1) xnext = bf2f(xp[(size_t)(tl + 1) * CONVD]);
    float s = wdt[tl] * xv;
    const f32x4* bb = (const f32x4*)(&Bl[tl][0]);
#pragma unroll
    for (int n4 = 0; n4 < 16; ++n4) {
      f32x4 b4 = bb[n4];
      S[n4 * 4 + 0] = fmaf(s, b4[0], S[n4 * 4 + 0]);
      S[n4 * 4 + 1] = fmaf(s, b4[1], S[n4 * 4 + 1]);
      S[n4 * 4 + 2] = fmaf(s, b4[2], S[n4 * 4 + 2]);
      S[n4 * 4 + 3] = fmaf(s, b4[3], S[n4 * 4 + 3]);
    }
  }
  float* dst = Sg + ((size_t)blk * 256 + tid) * 64;
#pragma unroll
  for (int n4 = 0; n4 < 16; ++n4) {
    f32x4 v = { S[n4 * 4], S[n4 * 4 + 1], S[n4 * 4 + 2], S[n4 * 4 + 3] };
    ((f32x4*)dst)[n4] = v;
  }
}

// ---------------- scan pass B: inter-chunk combine ----------------
__global__ __launch_bounds__(256)
void scan_passB(const float* __restrict__ Sg, const float* __restrict__ Pg,
                const float* __restrict__ init, float* __restrict__ Hg) {
  int blk = blockIdx.x;  // bh*16 + ptile
  int ptile = blk & 15, bh = blk >> 4;
  int h = bh & (NH - 1);
  int tid = threadIdx.x;
  size_t off = (size_t)ptile * 1024 + tid * 4;  // within 16384-elem state
  f32x4 hc = *(const f32x4*)(init + (size_t)h * HD * NS + off);
#pragma unroll 1
  for (int c = 0; c < NC; ++c) {
    *(f32x4*)(Hg + (size_t)(bh * NC + c) * 16384 + off) = hc;
    float P = Pg[bh * NC + c];
    f32x4 s = *(const f32x4*)(Sg + (size_t)(bh * NC + c) * 16384 + off);
    hc = P * hc + s;
  }
}

// ---------------- scan pass C: within-chunk recurrence + outputs ----------------
__global__ __launch_bounds__(256)
void scan_passC(const short* __restrict__ xbc, const float* __restrict__ dtg,
                const float* __restrict__ dag, const float* __restrict__ Hg,
                const float* __restrict__ Dp, short* __restrict__ yfull) {
  __shared__ alignas(16) float Bl[QC][NS];
  __shared__ alignas(16) float Cl[QC][NS];
  __shared__ float dAl[QC], dtl[QC];
  int blk = blockIdx.x;
  int c = blk & (NC - 1), bh = blk >> 3, h = bh & (NH - 1), b = bh >> 3;
  int tid = threadIdx.x;
  int rowbase = b * SEQLEN + c * QC;
  for (int j = tid; j < QC * NS; j += 256) {
    int tl = j >> 6, n = j & 63;
    const short* src = xbc + (size_t)(rowbase + tl) * CONVD + DINNER;
    Bl[tl][n] = bf2f(src[n]);
    Cl[tl][n] = bf2f(src[NS + n]);
  }
  dAl[tid] = dag[(rowbase + tid) * NH + h];
  dtl[tid] = dtg[(rowbase + tid) * NH + h];
  __syncthreads();
  float hst[NS];
  const float* hp = Hg + (size_t)blk * 16384 + tid * 64;
#pragma unroll
  for (int n4 = 0; n4 < 16; ++n4) {
    f32x4 v = ((const f32x4*)hp)[n4];
    hst[n4 * 4] = v[0]; hst[n4 * 4 + 1] = v[1];
    hst[n4 * 4 + 2] = v[2]; hst[n4 * 4 + 3] = v[3];
  }
  float Dh = Dp[h];
  const short* xp = xbc + (size_t)rowbase * CONVD + h * HD + tid;
  short* yp = yfull + (size_t)rowbase * DINNER + h * HD + tid;
  float xnext = bf2f(xp[0]);
  for (int tl = 0; tl < QC; ++tl) {
    float xv = xnext;
    if (tl < QC - 1) xnext = bf2f(xp[(size_t)(tl + 1) * CONVD]);
    float dAt = dAl[tl];
    float s = dtl[tl] * xv;
    const f32x4* bb = (const f32x4*)(&Bl[tl][0]);
    const f32x4* cc = (const f32x4*)(&Cl[tl][0]);
    float y0 = 0.f, y1 = 0.f, y2 = 0.f, y3 = 0.f;
#pragma unroll
    for (int n4 = 0; n4 < 16; ++n4) {
      f32x4 b4 = bb[n4], c4 = cc[n4];
      float h0 = fmaf(hst[n4 * 4 + 0], dAt, s * b4[0]); hst[n4 * 4 + 0] = h0; y0 = fmaf(h0, c4[0], y0);
      float h1 = fmaf(hst[n4 * 4 + 1], dAt, s * b4[1]); hst[n4 * 4 + 1] = h1; y1 = fmaf(h1, c4[1], y1);
      float h2 = fmaf(hst[n4 * 4 + 2], dAt, s * b4[2]); hst[n4 * 4 + 2] = h2; y2 = fmaf(h2, c4[2], y2);
      float h3 = fmaf(hst[n4 * 4 + 3], dAt, s * b4[3]); hst[n4 * 4 + 3] = h3; y3 = fmaf(h3, c4[3], y3);
    }
    yp[(size_t)tl * DINNER] = f2bf((y0 + y1) + (y2 + y3) + Dh * xv);
  }
}

// ---------------- gate (silu(z)) + RMSNorm -> bf16 ----------------
__global__ __launch_bounds__(256)
void gate_norm_kernel(const short* __restrict__ yfull, const short* __restrict__ zxb,
                      const float* __restrict__ norm_w, short* __restrict__ yn) {
  int row = blockIdx.x, tid = threadIdx.x;
  size_t yb = (size_t)row * DINNER, zb = (size_t)row * LDZX;
  float v[8];
  float ss = 0.f;
#pragma unroll
  for (int g = 0; g < 2; ++g) {
    int cidx = g * 1024 + tid * 4;
    short4v y4 = *(const short4v*)(yfull + yb + cidx);
    short4v z4 = *(const short4v*)(zxb + zb + cidx);
#pragma unroll
    for (int j = 0; j < 4; ++j) {
      float z = bf2f(z4[j]);
      float val = bf2f(y4[j]) * z * sigmoidf_fast(z);
      v[g * 4 + j] = val;
      ss = fmaf(val, val, ss);
    }
  }
#pragma unroll
  for (int o = 32; o; o >>= 1) ss += __shfl_down(ss, o);
  __shared__ float red[4];
  if ((tid & 63) == 0) red[tid >> 6] = ss;
  __syncthreads();
  float tot = red[0] + red[1] + red[2] + red[3];
  float scale = rsqrtf(tot * (1.f / (float)DINNER) + 1e-5f);
#pragma unroll
  for (int g = 0; g < 2; ++g) {
    int cidx = g * 1024 + tid * 4;
    short4v o4;
#pragma unroll
    for (int j = 0; j < 4; ++j) o4[j] = f2bf(v[g * 4 + j] * scale * norm_w[cidx + j]);
    *(short4v*)(yn + yb + cidx) = o4;
  }
}

// ---------------- launcher ----------------
extern "C" void kernel_launch(void* const* d_in, const int* in_sizes, int n_in,
                              void* d_out, int out_size, void* d_ws, size_t ws_size,
                              hipStream_t stream) {
  (void)in_sizes; (void)n_in; (void)out_size; (void)ws_size;
  const float* x     = (const float*)d_in[0];
  const float* W_in  = (const float*)d_in[1];
  const float* convw = (const float*)d_in[2];
  const float* convb = (const float*)d_in[3];
  const float* dtb   = (const float*)d_in[4];
  const float* Alog  = (const float*)d_in[5];
  const float* Dp    = (const float*)d_in[6];
  const float* inis  = (const float*)d_in[7];
  const float* nw    = (const float*)d_in[8];
  const float* W_out = (const float*)d_in[9];
  const float* W_nl  = (const float*)d_in[10];
  const float* b_nl  = (const float*)d_in[11];
  float* out = (float*)d_out;
  char* ws = (char*)d_ws;

  short* winT  = (short*)(ws + O_WIN);
  short* woutT = (short*)(ws + O_WOUT);
  short* wnlT  = (short*)(ws + O_WNL);
  float* dtg   = (float*)(ws + O_DT);
  float* dag   = (float*)(ws + O_DA);
  float* Pg    = (float*)(ws + O_P);
  short* xbf   = (short*)(ws + O_XBF);
  short* zxb   = (short*)(ws + O_ZXB);
  short* xbc   = (short*)(ws + O_XBC);
  float* Hg    = (float*)(ws + O_HG);
  float* Sg    = (float*)(ws + O_S);
  short* tb    = (short*)(ws + O_TB);
  short* yn    = (short*)(ws + O_YN);
  short* yfull = (short*)d_out;  // 8192*2048 bf16 == out_size*4 bytes exactly

  cast_x_kernel<<<8192, 256, 0, stream>>>(x, xbf);
  cast_winT_kernel<<<(4352 * 1024) / 256, 256, 0, stream>>>(W_in, winT);
  cast_woutT_kernel<<<(1024 * 2048) / 256, 256, 0, stream>>>(W_out, woutT);
  cast_wnlT_kernel<<<(1024 * 1024) / 256, 256, 0, stream>>>(W_nl, wnlT);
  dt_kernel<<<ROWS, 256, 0, stream>>>(x, W_in, dtb, Alog, dtg, dag);

  gemm_bf16<3><<<64 * 34, 256, 0, stream>>>(xbf, winT, HM, 34, LDZX, nullptr, zxb, nullptr, nullptr);
  conv_silu_kernel<<<17 * 32 * 4, 256, 0, stream>>>(zxb, convw, convb, xbc);

  scan_passA<<<32 * NC, 256, 0, stream>>>(xbc, dtg, dag, Sg, Pg);
  scan_passB<<<32 * 16, 256, 0, stream>>>(Sg, Pg, inis, Hg);
  scan_passC<<<32 * NC, 256, 0, stream>>>(xbc, dtg, dag, Hg, Dp, yfull);

  gate_norm_kernel<<<ROWS, 256, 0, stream>>>(yfull, zxb, nw, yn);
  gemm_bf16<1><<<64 * 8, 256, 0, stream>>>(yn, woutT, DINNER, 8, HM, nullptr, tb, nullptr, nullptr);
  gemm_bf16<2><<<64 * 8, 256, 0, stream>>>(tb, wnlT, HM, 8, HM, out, nullptr, b_nl, x);
}

// Round 4
// 424.920 us; speedup vs baseline: 2.5530x; 1.2605x over previous
//
#include <hip/hip_runtime.h>
#include <stdint.h>
#include <stddef.h>

// ---------------- problem dims ----------------
#define BATCH   4
#define SEQLEN  2048
#define HM      1024
#define DINNER  2048
#define NH      8
#define HD      256
#define NS      64
#define CONVD   2176
#define DCONV   16
#define DPROJ   4232
#define ROWS    (BATCH*SEQLEN)  // 8192
#define QC      256             // big-chunk length
#define NC      (SEQLEN/QC)     // 8 big-chunks
#define SC      64              // sub-chunk length (passC)
#define TT      16              // conv timesteps per thread

typedef __attribute__((ext_vector_type(8))) short short8;
typedef __attribute__((ext_vector_type(4))) short short4v;
typedef __attribute__((ext_vector_type(4))) float f32x4;

// ---------------- workspace layout (bytes), peak ~139.5 MiB ----------------
// lifetimes: winT,xbf -> GEMM1; zb -> gate_norm; xbcpre -> conv (then Sg/Hg, then tb);
// xbc -> passC (then yn); xT,bT -> passC; Hg -> passC.
static constexpr size_t O_WOUT   = 0;                    //  4,194,304
static constexpr size_t O_WNL    = 4194304;              //  2,097,152
static constexpr size_t O_DT     = 6291456;              //    262,144
static constexpr size_t O_LDA    = 6553600;              //    262,144
static constexpr size_t O_PG     = 6815744;              //      4,096
static constexpr size_t O_BT     = 6819840;              //  1,048,576
static constexpr size_t O_ZB     = 7868416;              // 33,554,432  bf16 z[8192][2048]
static constexpr size_t O_XBCPRE = 41422848;             // 35,651,584  bf16 [8192][2176]
static constexpr size_t O_SG     = O_XBCPRE;             // 16,777,216  f32 [65536][64]
static constexpr size_t O_HG     = O_XBCPRE + 16777216;  // 16,777,216  f32 [256][16384]
static constexpr size_t O_TB     = O_XBCPRE;             // 16,777,216  bf16 [8192][1024]
static constexpr size_t O_XBC    = 77074432;             // 35,651,584  bf16 [8192][2176]
static constexpr size_t O_YN     = O_XBC;                // 33,554,432  bf16 [8192][2048]
static constexpr size_t O_XTR    = 112726016;            // 33,554,432  bf16 xT[2048][8192]
static constexpr size_t O_XBF    = O_XTR;                // 16,777,216  bf16 [8192][1024]
static constexpr size_t O_WIN    = O_XTR + 16777216;     //  8,912,896  bf16 [4352][1024]
// END = 146,280,448

// ---------------- helpers ----------------
__device__ __forceinline__ short f2bf(float f) {
  union { float f; uint32_t u; } v; v.f = f;
  uint32_t r = v.u + 0x7fffu + ((v.u >> 16) & 1u);
  return (short)(r >> 16);
}

__device__ __forceinline__ float bf2f(short s) {
  union { float f; uint32_t u; } v;
  v.u = ((uint32_t)(uint16_t)s) << 16;
  return v.f;
}

__device__ __forceinline__ void gload_lds16(const void* g, void* l) {
  __builtin_amdgcn_global_load_lds(
      (const __attribute__((address_space(1))) uint32_t*)g,
      (__attribute__((address_space(3))) uint32_t*)l, 16, 0, 0);
}

__device__ __forceinline__ float sigmoidf_fast(float x) {
  return 1.f / (1.f + __expf(-x));
}

// fragment read from a [rows][64-elem] bf16 LDS tile (128B rows, XOR-swizzled)
__device__ __forceinline__ short8 fragr(const char* base, int row, int kbyte) {
  return *(const short8*)(base + row * 128 + (kbyte ^ ((row & 7) << 4)));
}

// ---------------- cast kernels ----------------
__global__ __launch_bounds__(256) void cast_x_kernel(const float* __restrict__ x,
                                                     short* __restrict__ xb) {
  int i = blockIdx.x * 256 + threadIdx.x;
  f32x4 v = ((const f32x4*)x)[i];
  short4v o = { f2bf(v[0]), f2bf(v[1]), f2bf(v[2]), f2bf(v[3]) };
  ((short4v*)xb)[i] = o;
}

__global__ __launch_bounds__(256) void cast_winT_kernel(const float* __restrict__ W,
                                                        short* __restrict__ Wt) {
  int i = blockIdx.x * 256 + threadIdx.x;  // Wt[n][k], n<4352
  int n = i >> 10, k = i & 1023;
  float v = (n < DPROJ) ? W[(size_t)k * DPROJ + n] : 0.f;
  Wt[i] = f2bf(v);
}

__global__ __launch_bounds__(256) void cast_woutT_kernel(const float* __restrict__ W,
                                                         short* __restrict__ Wt) {
  int i = blockIdx.x * 256 + threadIdx.x;  // Wt[n][k], k in 2048
  int n = i >> 11, k = i & 2047;
  Wt[i] = f2bf(W[(size_t)k * HM + n]);
}

__global__ __launch_bounds__(256) void cast_wnlT_kernel(const float* __restrict__ W,
                                                        short* __restrict__ Wt) {
  int i = blockIdx.x * 256 + threadIdx.x;
  int n = i >> 10, k = i & 1023;
  Wt[i] = f2bf(W[(size_t)k * HM + n]);
}

// ---------------- dt in f32 (exp-amplified path, exact) ----------------
__global__ __launch_bounds__(256) void dt_kernel(const float* __restrict__ x,
                                                 const float* __restrict__ W_in,
                                                 const float* __restrict__ dt_bias,
                                                 const float* __restrict__ A_log,
                                                 float* __restrict__ dtg,
                                                 float* __restrict__ ldA) {
  int row = blockIdx.x, tid = threadIdx.x;
  float p[NH];
#pragma unroll
  for (int h = 0; h < NH; ++h) p[h] = 0.f;
  for (int k = tid; k < HM; k += 256) {
    float xv = x[(size_t)row * HM + k];
    const float* w = &W_in[(size_t)k * DPROJ + (DPROJ - NH)];
#pragma unroll
    for (int h = 0; h < NH; ++h) p[h] = fmaf(xv, w[h], p[h]);
  }
#pragma unroll
  for (int h = 0; h < NH; ++h)
#pragma unroll
    for (int o = 32; o; o >>= 1) p[h] += __shfl_down(p[h], o);
  __shared__ float red[4][NH];
  int lane = tid & 63, w4 = tid >> 6;
  if (lane == 0)
#pragma unroll
    for (int h = 0; h < NH; ++h) red[w4][h] = p[h];
  __syncthreads();
  if (tid < NH) {
    float s = red[0][tid] + red[1][tid] + red[2][tid] + red[3][tid] + dt_bias[tid];
    float dtv = (s > 20.f) ? s : log1pf(expf(s));
    float A = -expf(A_log[tid]);
    dtg[row * NH + tid] = dtv;
    ldA[row * NH + tid] = dtv * A;
  }
}

// ---------------- bf16 MFMA GEMM, 128x128 tile, BK=64 ----------------
// A [M][K] bf16 row-major, B [N][K] bf16 row-major.
// EPI 1: t=y*rsqrt(1+y^2)->bf16  EPI 2: y+bias+resid->f32  EPI 4: split zb/xbcpre
template <int EPI>
__global__ __launch_bounds__(256)
void gemm_bf16(const short* __restrict__ A, const short* __restrict__ B,
               int K, int nTilesN, int N_out,
               float* __restrict__ Cf, short* __restrict__ Cb,
               const float* __restrict__ bias, const float* __restrict__ resid,
               short* __restrict__ Cb2) {
  __shared__ alignas(16) char lds[32768];
  char* As = lds;
  char* Bs = lds + 16384;
  const int tid = threadIdx.x;
  const int bid = blockIdx.x;
  const int m0 = (bid / nTilesN) * 128;
  const int n0 = (bid % nTilesN) * 128;
  const int lane = tid & 63;
  const int wave = tid >> 6;
  const int wr = wave >> 1, wc = wave & 1;
  const int lrow = lane & 15, lk = lane >> 4;

  f32x4 acc[4][4];
#pragma unroll
  for (int i = 0; i < 4; ++i)
#pragma unroll
    for (int j = 0; j < 4; ++j) acc[i][j] = (f32x4)0.f;

  for (int k0 = 0; k0 < K; k0 += 64) {
#pragma unroll
    for (int r = 0; r < 4; ++r) {
      int p = r * 4096 + tid * 16;
      int row = p >> 7, c = p & 127;
      int sc = c ^ ((row & 7) << 4);
      gload_lds16((const char*)A + ((size_t)(m0 + row) * K + k0) * 2 + sc, As + p);
      gload_lds16((const char*)B + ((size_t)(n0 + row) * K + k0) * 2 + sc, Bs + p);
    }
    asm volatile("s_waitcnt vmcnt(0)" ::: "memory");
    __syncthreads();
#pragma unroll
    for (int ks = 0; ks < 2; ++ks) {
      short8 av[4], bv[4];
#pragma unroll
      for (int i = 0; i < 4; ++i) {
        av[i] = fragr(As, wr * 64 + i * 16 + lrow, ks * 64 + lk * 16);
        bv[i] = fragr(Bs, wc * 64 + i * 16 + lrow, ks * 64 + lk * 16);
      }
#pragma unroll
      for (int i = 0; i < 4; ++i)
#pragma unroll
        for (int j = 0; j < 4; ++j)
          acc[i][j] = __builtin_amdgcn_mfma_f32_16x16x32_bf16(av[i], bv[j], acc[i][j], 0, 0, 0);
    }
    __syncthreads();
  }

  const int row0 = m0 + wr * 64, col0 = n0 + wc * 64;
#pragma unroll
  for (int i = 0; i < 4; ++i)
#pragma unroll
    for (int j = 0; j < 4; ++j)
#pragma unroll
      for (int r = 0; r < 4; ++r) {
        int row = row0 + i * 16 + lk * 4 + r;
        int col = col0 + j * 16 + lrow;
        float v = acc[i][j][r];
        if (EPI == 1) {
          float t = v * rsqrtf(1.f + v * v);
          Cb[(size_t)row * N_out + col] = f2bf(t);
        } else if (EPI == 2) {
          Cf[(size_t)row * N_out + col] = v + bias[col] + resid[(size_t)row * N_out + col];
        } else {  // EPI 4: cols<2048 -> Cb (zb, stride 2048); 2048..4223 -> Cb2 (xbcpre)
          if (col < DINNER) Cb[(size_t)row * DINNER + col] = f2bf(v);
          else if (col < DINNER + CONVD) Cb2[(size_t)row * CONVD + (col - DINNER)] = f2bf(v);
        }
      }
}

// ---------------- depthwise causal conv16 + SiLU, register-blocked ----------
// also emits xT[ch][row] for x-channels and bT[n][row] for B-channels
__global__ __launch_bounds__(256) void conv_silu_kernel(const short* __restrict__ xbcpre,
                                                        const float* __restrict__ cw,
                                                        const float* __restrict__ cbias,
                                                        short* __restrict__ xbc,
                                                        short* __restrict__ xT,
                                                        short* __restrict__ bTg) {
  int blk = blockIdx.x;            // 17*32*4
  int cg = blk % 17;
  int tg = (blk / 17) % 32;
  int b  = blk / (17 * 32);
  int lane = threadIdx.x & 63;
  int warp = threadIdx.x >> 6;
  int cp = cg * 64 + lane;
  int c0 = cp * 2;
  int tbase = (tg * 4 + warp) * TT;

  const short* inp = xbcpre + (size_t)(b * SEQLEN) * CONVD + c0;
  uint32_t in[TT + DCONV - 1];
#pragma unroll
  for (int j = 0; j < TT + DCONV - 1; ++j) {
    int t = tbase + j - (DCONV - 1);
    in[j] = (t >= 0) ? *(const uint32_t*)(inp + (size_t)t * CONVD) : 0u;
  }
  float w0[DCONV], w1[DCONV];
  const float* wp = cw + (size_t)c0 * DCONV;
#pragma unroll
  for (int k = 0; k < DCONV; ++k) { w0[k] = wp[k]; w1[k] = wp[DCONV + k]; }
  float bb0 = cbias[c0], bb1 = cbias[c0 + 1];

  short o0[TT], o1[TT];
  short* outp = xbc + (size_t)(b * SEQLEN) * CONVD + c0;
#pragma unroll
  for (int tt = 0; tt < TT; ++tt) {
    float a0 = bb0, a1 = bb1;
#pragma unroll
    for (int k = 0; k < DCONV; ++k) {
      uint32_t v = in[tt + k];
      a0 = fmaf(bf2f((short)(v & 0xffffu)), w0[k], a0);
      a1 = fmaf(bf2f((short)(v >> 16)), w1[k], a1);
    }
    a0 = a0 * sigmoidf_fast(a0);
    a1 = a1 * sigmoidf_fast(a1);
    short s0v = f2bf(a0), s1v = f2bf(a1);
    o0[tt] = s0v; o1[tt] = s1v;
    uint32_t o = (uint32_t)(uint16_t)s0v | ((uint32_t)(uint16_t)s1v << 16);
    *(uint32_t*)(outp + (size_t)(tbase + tt) * CONVD) = o;
  }
  int grow = b * SEQLEN + tbase;
  short* dst = nullptr;
  if (c0 < DINNER) dst = xT + (size_t)c0 * ROWS + grow;
  else if (c0 < DINNER + NS) dst = bTg + (size_t)(c0 - DINNER) * ROWS + grow;
  if (dst) {
    short8 v0a = { o0[0], o0[1], o0[2], o0[3], o0[4], o0[5], o0[6], o0[7] };
    short8 v0b = { o0[8], o0[9], o0[10], o0[11], o0[12], o0[13], o0[14], o0[15] };
    short8 v1a = { o1[0], o1[1], o1[2], o1[3], o1[4], o1[5], o1[6], o1[7] };
    short8 v1b = { o1[8], o1[9], o1[10], o1[11], o1[12], o1[13], o1[14], o1[15] };
    *(short8*)(dst) = v0a;
    *(short8*)(dst + 8) = v0b;
    *(short8*)(dst + ROWS) = v1a;
    *(short8*)(dst + ROWS + 8) = v1b;
  }
}

// ---------------- scan pass A (MFMA): big-chunk state contribution ----------
// S[p][n] = sum_s exp(a_last - a_s) dt_s x_s[p] B_s[n]; Pg = exp(a_last)
__global__ __launch_bounds__(256)
void scan_passA_mfma(const short* __restrict__ xT, const short* __restrict__ bTg,
                     const float* __restrict__ dtg, const float* __restrict__ ldA,
                     float* __restrict__ Sg, float* __restrict__ Pg) {
  __shared__ alignas(16) char Ax[32768];   // [256p][64s] (scaled in place)
  __shared__ alignas(16) char Bt[8192];    // [64n][64s]
  __shared__ float aa[QC + 1];
  __shared__ float wdt[QC];
  int blk = blockIdx.x;
  int c8 = blk & 7, bh = blk >> 3;
  int h = bh & 7, b = bh >> 3;
  int tid = threadIdx.x, wave = tid >> 6, lane = tid & 63;
  int lrow = lane & 15, lk = lane >> 4;
  int rowbase = b * SEQLEN + c8 * QC;
  if (tid == 0) {
    float s = 0.f; aa[0] = 0.f;
    for (int t = 0; t < QC; ++t) { s += ldA[(rowbase + t) * NH + h]; aa[t + 1] = s; }
    Pg[blk] = __expf(s);
  }
  __syncthreads();
  float alast = aa[QC];
  wdt[tid] = __expf(alast - aa[tid + 1]) * dtg[(rowbase + tid) * NH + h];

  f32x4 acc[4][4];
#pragma unroll
  for (int i = 0; i < 4; ++i)
#pragma unroll
    for (int j = 0; j < 4; ++j) acc[i][j] = (f32x4)0.f;

  for (int ks = 0; ks < 4; ++ks) {
    int s0 = ks * 64;
#pragma unroll
    for (int it = 0; it < 8; ++it) {
      int p = it * 4096 + tid * 16;
      int row = p >> 7, c = p & 127;
      int sc = c ^ ((row & 7) << 4);
      gload_lds16((const char*)(xT + (size_t)(h * HD + row) * ROWS + rowbase + s0) + sc, Ax + p);
    }
#pragma unroll
    for (int it = 0; it < 2; ++it) {
      int p = it * 4096 + tid * 16;
      int row = p >> 7, c = p & 127;
      int sc = c ^ ((row & 7) << 4);
      gload_lds16((const char*)(bTg + (size_t)row * ROWS + rowbase + s0) + sc, Bt + p);
    }
    asm volatile("s_waitcnt vmcnt(0)" ::: "memory");
    __syncthreads();
    {  // scale own row (p = tid) by wdt
      int row = tid;
#pragma unroll
      for (int g = 0; g < 8; ++g) {
        int off = row * 128 + g * 16;
        int sb = s0 + (((g * 16) ^ ((row & 7) << 4)) >> 1);
        short8 v = *(short8*)(Ax + off);
        short8 o;
#pragma unroll
        for (int j = 0; j < 8; ++j) o[j] = f2bf(bf2f(v[j]) * wdt[sb + j]);
        *(short8*)(Ax + off) = o;
      }
    }
    __syncthreads();
#pragma unroll
    for (int kk = 0; kk < 2; ++kk) {
      short8 av[4], bv[4];
#pragma unroll
      for (int i = 0; i < 4; ++i) {
        av[i] = fragr(Ax, wave * 64 + i * 16 + lrow, kk * 64 + lk * 16);
        bv[i] = fragr(Bt, i * 16 + lrow, kk * 64 + lk * 16);
      }
#pragma unroll
      for (int i = 0; i < 4; ++i)
#pragma unroll
        for (int j = 0; j < 4; ++j)
          acc[i][j] = __builtin_amdgcn_mfma_f32_16x16x32_bf16(av[i], bv[j], acc[i][j], 0, 0, 0);
    }
    __syncthreads();
  }
#pragma unroll
  for (int i = 0; i < 4; ++i)
#pragma unroll
    for (int j = 0; j < 4; ++j)
#pragma unroll
      for (int r = 0; r < 4; ++r) {
        int p = wave * 64 + i * 16 + lk * 4 + r;
        int n = j * 16 + lrow;
        Sg[((size_t)blk * 256 + p) * 64 + n] = acc[i][j][r];
      }
}

// ---------------- scan pass B: inter-chunk combine (f32, unchanged) --------
__global__ __launch_bounds__(256)
void scan_passB(const float* __restrict__ Sg, const float* __restrict__ Pg,
                const float* __restrict__ init, float* __restrict__ Hg) {
  int blk = blockIdx.x;  // bh*16 + ptile
  int ptile = blk & 15, bh = blk >> 4;
  int h = bh & (NH - 1);
  int tid = threadIdx.x;
  size_t off = (size_t)ptile * 1024 + tid * 4;
  f32x4 hc = *(const f32x4*)(init + (size_t)h * HD * NS + off);
#pragma unroll 1
  for (int c = 0; c < NC; ++c) {
    *(f32x4*)(Hg + (size_t)(bh * NC + c) * 16384 + off) = hc;
    float P = Pg[bh * NC + c];
    f32x4 s = *(const f32x4*)(Sg + (size_t)(bh * NC + c) * 16384 + off);
    hc = P * hc + s;
  }
}

// ---------------- scan pass C (MFMA): chunked y computation ----------------
__global__ __launch_bounds__(256)
void scan_passC_mfma(const short* __restrict__ xT, const short* __restrict__ bTg,
                     const short* __restrict__ xbc,
                     const float* __restrict__ dtg, const float* __restrict__ ldA,
                     const float* __restrict__ Hg, const float* __restrict__ Dp,
                     short* __restrict__ yfull) {
  __shared__ alignas(16) char Xb[32768];   // [256p][64s] raw x then scaled
  __shared__ alignas(16) char Hb[32768];   // [256p][64n] h (bf16)
  __shared__ alignas(16) char Bn[8192];    // [64s][64n]
  __shared__ alignas(16) char Cn[8192];    // [64t][64n] raw C then Ce
  __shared__ alignas(16) char Bt2[8192];   // [64n][64s]
  __shared__ alignas(16) char Mm[8192];    // [64t][64s]
  __shared__ float aa[QC + 1];
  __shared__ float dts[QC];
  int blk = blockIdx.x;
  int c8 = blk & 7, bh = blk >> 3;
  int h = bh & 7, b = bh >> 3;
  int tid = threadIdx.x, wave = tid >> 6, lane = tid & 63;
  int lrow = lane & 15, lk = lane >> 4;
  int rowbase = b * SEQLEN + c8 * QC;
  if (tid == 0) {
    float s = 0.f; aa[0] = 0.f;
    for (int t = 0; t < QC; ++t) { s += ldA[(rowbase + t) * NH + h]; aa[t + 1] = s; }
  }
  dts[tid] = dtg[(rowbase + tid) * NH + h];
  __syncthreads();
  float Dh = Dp[h];

  // h0 into accumulators: hcc[i][j][r] = h[p][n], p=wave*64+i*16+lk*4+r, n=j*16+lrow
  f32x4 hcc[4][4];
  const float* hp = Hg + (size_t)blk * 16384;
#pragma unroll
  for (int i = 0; i < 4; ++i)
#pragma unroll
    for (int j = 0; j < 4; ++j)
#pragma unroll
      for (int r = 0; r < 4; ++r)
        hcc[i][j][r] = hp[(size_t)(wave * 64 + i * 16 + lk * 4 + r) * 64 + j * 16 + lrow];

  for (int sc = 0; sc < 4; ++sc) {
    int s0 = sc * SC;
    // (0) h -> Hb bf16 (wave-local rows)
#pragma unroll
    for (int i = 0; i < 4; ++i)
#pragma unroll
      for (int j = 0; j < 4; ++j)
#pragma unroll
        for (int r = 0; r < 4; ++r) {
          int p = wave * 64 + i * 16 + lk * 4 + r;
          int n = j * 16 + lrow;
          *(short*)(Hb + p * 128 + ((n * 2) ^ ((p & 7) << 4))) = f2bf(hcc[i][j][r]);
        }
    // (1) stage Xb, Bn, Cn, Bt2
#pragma unroll
    for (int it = 0; it < 8; ++it) {
      int p = it * 4096 + tid * 16;
      int row = p >> 7, c = p & 127;
      int scz = c ^ ((row & 7) << 4);
      gload_lds16((const char*)(xT + (size_t)(h * HD + row) * ROWS + rowbase + s0) + scz, Xb + p);
    }
#pragma unroll
    for (int it = 0; it < 2; ++it) {
      int p = it * 4096 + tid * 16;
      int row = p >> 7, c = p & 127;
      int scz = c ^ ((row & 7) << 4);
      gload_lds16((const char*)(xbc + (size_t)(rowbase + s0 + row) * CONVD + DINNER) + scz, Bn + p);
      gload_lds16((const char*)(xbc + (size_t)(rowbase + s0 + row) * CONVD + DINNER + NS) + scz, Cn + p);
      gload_lds16((const char*)(bTg + (size_t)row * ROWS + rowbase + s0) + scz, Bt2 + p);
    }
    asm volatile("s_waitcnt vmcnt(0)" ::: "memory");
    __syncthreads();  // S1

    // (2) G = C * B^T, wave computes t-rows [16w,16w+16)
    f32x4 gcc[4];
#pragma unroll
    for (int j = 0; j < 4; ++j) gcc[j] = (f32x4)0.f;
#pragma unroll
    for (int kk = 0; kk < 2; ++kk) {
      short8 avc = fragr(Cn, wave * 16 + lrow, kk * 64 + lk * 16);
#pragma unroll
      for (int j = 0; j < 4; ++j) {
        short8 bvb = fragr(Bn, j * 16 + lrow, kk * 64 + lk * 16);
        gcc[j] = __builtin_amdgcn_mfma_f32_16x16x32_bf16(avc, bvb, gcc[j], 0, 0, 0);
      }
    }
    // (3) M write (wave rows) + Ce scale (wave-local rows)
#pragma unroll
    for (int j = 0; j < 4; ++j)
#pragma unroll
      for (int r = 0; r < 4; ++r) {
        int t = wave * 16 + lk * 4 + r;
        int s = j * 16 + lrow;
        float val = (s <= t) ? gcc[j][r] * __expf(aa[s0 + t + 1] - aa[s0 + s + 1]) * dts[s0 + s]
                             : 0.f;
        *(short*)(Mm + t * 128 + ((s * 2) ^ ((t & 7) << 4))) = f2bf(val);
      }
#pragma unroll
    for (int pass = 0; pass < 2; ++pass) {  // scale Cn rows [16w..16w+16) by exp(a_t - a_{s0-1})
      int t = wave * 16 + (lane >> 3) + pass * 8;
      int g = lane & 7;
      int off = t * 128 + g * 16;
      float fac = __expf(aa[s0 + t + 1] - aa[s0]);
      short8 v = *(short8*)(Cn + off);
      short8 o;
#pragma unroll
      for (int j = 0; j < 8; ++j) o[j] = f2bf(bf2f(v[j]) * fac);
      *(short8*)(Cn + off) = o;
    }
    __syncthreads();  // S2

    // (4)(5) Y = M@X + Ce@h for this wave's p-slab
    f32x4 ycc[4][4];
#pragma unroll
    for (int i = 0; i < 4; ++i)
#pragma unroll
      for (int j = 0; j < 4; ++j) ycc[i][j] = (f32x4)0.f;
#pragma unroll
    for (int kk = 0; kk < 2; ++kk) {
      short8 av[4], bv[4];
#pragma unroll
      for (int i = 0; i < 4; ++i) {
        av[i] = fragr(Mm, i * 16 + lrow, kk * 64 + lk * 16);
        bv[i] = fragr(Xb, wave * 64 + i * 16 + lrow, kk * 64 + lk * 16);
      }
#pragma unroll
      for (int i = 0; i < 4; ++i)
#pragma unroll
        for (int j = 0; j < 4; ++j)
          ycc[i][j] = __builtin_amdgcn_mfma_f32_16x16x32_bf16(av[i], bv[j], ycc[i][j], 0, 0, 0);
    }
#pragma unroll
    for (int kk = 0; kk < 2; ++kk) {
      short8 av[4], bv[4];
#pragma unroll
      for (int i = 0; i < 4; ++i) {
        av[i] = fragr(Cn, i * 16 + lrow, kk * 64 + lk * 16);
        bv[i] = fragr(Hb, wave * 64 + i * 16 + lrow, kk * 64 + lk * 16);
      }
#pragma unroll
      for (int i = 0; i < 4; ++i)
#pragma unroll
        for (int j = 0; j < 4; ++j)
          ycc[i][j] = __builtin_amdgcn_mfma_f32_16x16x32_bf16(av[i], bv[j], ycc[i][j], 0, 0, 0);
    }
    // (6) epilogue: y = ycc + D*x (Xb still raw)
#pragma unroll
    for (int i = 0; i < 4; ++i)
#pragma unroll
      for (int j = 0; j < 4; ++j)
#pragma unroll
        for (int r = 0; r < 4; ++r) {
          int t = i * 16 + lk * 4 + r;
          int p = wave * 64 + j * 16 + lrow;
          float xv = bf2f(*(const short*)(Xb + p * 128 + ((t * 2) ^ ((p & 7) << 4))));
          yfull[(size_t)(rowbase + s0 + t) * DINNER + h * HD + p] = f2bf(ycc[i][j][r] + Dh * xv);
        }
    // (7) scale Xb in place by state weights (wave-local rows)
    {
      int row = tid;
      float aend = aa[s0 + SC];
#pragma unroll
      for (int g = 0; g < 8; ++g) {
        int off = row * 128 + g * 16;
        int sb = s0 + (((g * 16) ^ ((row & 7) << 4)) >> 1);
        short8 v = *(short8*)(Xb + off);
        short8 o;
#pragma unroll
        for (int j = 0; j < 8; ++j)
          o[j] = f2bf(bf2f(v[j]) * __expf(aend - aa[sb + j + 1]) * dts[sb + j]);
        *(short8*)(Xb + off) = o;
      }
    }
    // (8) state update: h = P_sub*h + Xw^T @ B
    {
      float Ps = __expf(aa[s0 + SC] - aa[s0]);
#pragma unroll
      for (int i = 0; i < 4; ++i)
#pragma unroll
        for (int j = 0; j < 4; ++j) hcc[i][j] *= Ps;
#pragma unroll
      for (int kk = 0; kk < 2; ++kk) {
        short8 av[4], bv[4];
#pragma unroll
        for (int i = 0; i < 4; ++i) {
          av[i] = fragr(Xb, wave * 64 + i * 16 + lrow, kk * 64 + lk * 16);
          bv[i] = fragr(Bt2, i * 16 + lrow, kk * 64 + lk * 16);
        }
#pragma unroll
        for (int i = 0; i < 4; ++i)
#pragma unroll
          for (int j = 0; j < 4; ++j)
            hcc[i][j] = __builtin_amdgcn_mfma_f32_16x16x32_bf16(av[i], bv[j], hcc[i][j], 0, 0, 0);
      }
    }
    __syncthreads();  // S3 (protect next sub's staging)
  }
}

// ---------------- gate (silu(z)) + RMSNorm -> bf16 ----------------
__global__ __launch_bounds__(256)
void gate_norm_kernel(const short* __restrict__ yfull, const short* __restrict__ zb,
                      const float* __restrict__ norm_w, short* __restrict__ yn) {
  int row = blockIdx.x, tid = threadIdx.x;
  size_t yb = (size_t)row * DINNER;
  float v[8];
  float ss = 0.f;
#pragma unroll
  for (int g = 0; g < 2; ++g) {
    int cidx = g * 1024 + tid * 4;
    short4v y4 = *(const short4v*)(yfull + yb + cidx);
    short4v z4 = *(const short4v*)(zb + yb + cidx);
#pragma unroll
    for (int j = 0; j < 4; ++j) {
      float z = bf2f(z4[j]);
      float val = bf2f(y4[j]) * z * sigmoidf_fast(z);
      v[g * 4 + j] = val;
      ss = fmaf(val, val, ss);
    }
  }
#pragma unroll
  for (int o = 32; o; o >>= 1) ss += __shfl_down(ss, o);
  __shared__ float red[4];
  if ((tid & 63) == 0) red[tid >> 6] = ss;
  __syncthreads();
  float tot = red[0] + red[1] + red[2] + red[3];
  float scale = rsqrtf(tot * (1.f / (float)DINNER) + 1e-5f);
#pragma unroll
  for (int g = 0; g < 2; ++g) {
    int cidx = g * 1024 + tid * 4;
    short4v o4;
#pragma unroll
    for (int j = 0; j < 4; ++j) o4[j] = f2bf(v[g * 4 + j] * scale * norm_w[cidx + j]);
    *(short4v*)(yn + yb + cidx) = o4;
  }
}

// ---------------- launcher ----------------
extern "C" void kernel_launch(void* const* d_in, const int* in_sizes, int n_in,
                              void* d_out, int out_size, void* d_ws, size_t ws_size,
                              hipStream_t stream) {
  (void)in_sizes; (void)n_in; (void)out_size; (void)ws_size;
  const float* x     = (const float*)d_in[0];
  const float* W_in  = (const float*)d_in[1];
  const float* convw = (const float*)d_in[2];
  const float* convb = (const float*)d_in[3];
  const float* dtb   = (const float*)d_in[4];
  const float* Alog  = (const float*)d_in[5];
  const float* Dp    = (const float*)d_in[6];
  const float* inis  = (const float*)d_in[7];
  const float* nw    = (const float*)d_in[8];
  const float* W_out = (const float*)d_in[9];
  const float* W_nl  = (const float*)d_in[10];
  const float* b_nl  = (const float*)d_in[11];
  float* out = (float*)d_out;
  char* ws = (char*)d_ws;

  short* woutT  = (short*)(ws + O_WOUT);
  short* wnlT   = (short*)(ws + O_WNL);
  float* dtg    = (float*)(ws + O_DT);
  float* ldA    = (float*)(ws + O_LDA);
  float* Pg     = (float*)(ws + O_PG);
  short* bTg    = (short*)(ws + O_BT);
  short* zb     = (short*)(ws + O_ZB);
  short* xbcpre = (short*)(ws + O_XBCPRE);
  float* Sg     = (float*)(ws + O_SG);
  float* Hg     = (float*)(ws + O_HG);
  short* tb     = (short*)(ws + O_TB);
  short* xbc    = (short*)(ws + O_XBC);
  short* yn     = (short*)(ws + O_YN);
  short* xT     = (short*)(ws + O_XTR);
  short* xbf    = (short*)(ws + O_XBF);
  short* winT   = (short*)(ws + O_WIN);
  short* yfull  = (short*)d_out;

  cast_x_kernel<<<8192, 256, 0, stream>>>(x, xbf);
  cast_winT_kernel<<<(4352 * 1024) / 256, 256, 0, stream>>>(W_in, winT);
  cast_woutT_kernel<<<(1024 * 2048) / 256, 256, 0, stream>>>(W_out, woutT);
  cast_wnlT_kernel<<<(1024 * 1024) / 256, 256, 0, stream>>>(W_nl, wnlT);
  dt_kernel<<<ROWS, 256, 0, stream>>>(x, W_in, dtb, Alog, dtg, ldA);

  gemm_bf16<4><<<64 * 34, 256, 0, stream>>>(xbf, winT, HM, 34, 0, nullptr, zb, nullptr, nullptr, xbcpre);
  conv_silu_kernel<<<17 * 32 * 4, 256, 0, stream>>>(xbcpre, convw, convb, xbc, xT, bTg);

  scan_passA_mfma<<<32 * NC, 256, 0, stream>>>(xT, bTg, dtg, ldA, Sg, Pg);
  scan_passB<<<32 * 16, 256, 0, stream>>>(Sg, Pg, inis, Hg);
  scan_passC_mfma<<<32 * NC, 256, 0, stream>>>(xT, bTg, xbc, dtg, ldA, Hg, Dp, yfull);

  gate_norm_kernel<<<ROWS, 256, 0, stream>>>(yfull, zb, nw, yn);
  gemm_bf16<1><<<64 * 8, 256, 0, stream>>>(yn, woutT, DINNER, 8, HM, nullptr, tb, nullptr, nullptr, nullptr);
  gemm_bf16<2><<<64 * 8, 256, 0, stream>>>(tb, wnlT, HM, 8, HM, out, nullptr, b_nl, x, nullptr);
}

// Round 5
// 407.218 us; speedup vs baseline: 2.6640x; 1.0435x over previous
//
#include <hip/hip_runtime.h>
#include <stdint.h>
#include <stddef.h>

// ---------------- problem dims ----------------
#define BATCH   4
#define SEQLEN  2048
#define HM      1024
#define DINNER  2048
#define NH      8
#define HD      256
#define NS      64
#define CONVD   2176
#define DCONV   16
#define DPROJ   4232
#define ROWS    (BATCH*SEQLEN)  // 8192
#define QC      256             // big-chunk length
#define NC      (SEQLEN/QC)     // 8 big-chunks
#define SC      64              // sub-chunk length (passC)
#define TT      16              // conv timesteps per thread

typedef __attribute__((ext_vector_type(8))) short short8;
typedef __attribute__((ext_vector_type(4))) short short4v;
typedef __attribute__((ext_vector_type(4))) float f32x4;

// ---------------- workspace layout (bytes), peak ~139.5 MiB ----------------
static constexpr size_t O_WOUT   = 0;                    //  4,194,304
static constexpr size_t O_WNL    = 4194304;              //  2,097,152
static constexpr size_t O_DT     = 6291456;              //    262,144
static constexpr size_t O_LDA    = 6553600;              //    262,144
static constexpr size_t O_PG     = 6815744;              //      4,096
static constexpr size_t O_BT     = 6819840;              //  1,048,576
static constexpr size_t O_ZB     = 7868416;              // 33,554,432  bf16 z[8192][2048]
static constexpr size_t O_XBCPRE = 41422848;             // 35,651,584  bf16 [8192][2176]
static constexpr size_t O_SG     = O_XBCPRE;             // 16,777,216  f32 [65536][64]
static constexpr size_t O_HG     = O_XBCPRE + 16777216;  // 16,777,216  f32 [256][16384]
static constexpr size_t O_TB     = O_XBCPRE;             // 16,777,216  bf16 [8192][1024]
static constexpr size_t O_XBC    = 77074432;             // 35,651,584  bf16 [8192][2176]
static constexpr size_t O_YN     = O_XBC;                // 33,554,432  bf16 [8192][2048]
static constexpr size_t O_XTR    = 112726016;            // 33,554,432  bf16 xT[2048][8192]
static constexpr size_t O_XBF    = O_XTR;                // 16,777,216  bf16 [8192][1024]
static constexpr size_t O_WIN    = O_XTR + 16777216;     //  8,912,896  bf16 [4352][1024]
// END = 146,280,448

// ---------------- helpers ----------------
__device__ __forceinline__ short f2bf(float f) {
  union { float f; uint32_t u; } v; v.f = f;
  uint32_t r = v.u + 0x7fffu + ((v.u >> 16) & 1u);
  return (short)(r >> 16);
}

__device__ __forceinline__ float bf2f(short s) {
  union { float f; uint32_t u; } v;
  v.u = ((uint32_t)(uint16_t)s) << 16;
  return v.f;
}

__device__ __forceinline__ void gload_lds16(const void* g, void* l) {
  __builtin_amdgcn_global_load_lds(
      (const __attribute__((address_space(1))) uint32_t*)g,
      (__attribute__((address_space(3))) uint32_t*)l, 16, 0, 0);
}

__device__ __forceinline__ float sigmoidf_fast(float x) {
  return 1.f / (1.f + __expf(-x));
}

// fragment read from a [rows][64-elem] bf16 LDS tile (128B rows, XOR-swizzled)
__device__ __forceinline__ short8 fragr(const char* base, int row, int kbyte) {
  return *(const short8*)(base + row * 128 + (kbyte ^ ((row & 7) << 4)));
}

// ---------------- cast x (row-major, coalesced) ----------------
__global__ __launch_bounds__(256) void cast_x_kernel(const float* __restrict__ x,
                                                     short* __restrict__ xb) {
  int i = blockIdx.x * 256 + threadIdx.x;
  f32x4 v = ((const f32x4*)x)[i];
  short4v o = { f2bf(v[0]), f2bf(v[1]), f2bf(v[2]), f2bf(v[3]) };
  ((short4v*)xb)[i] = o;
}

// ---------------- generic LDS-tiled transpose-cast -------------------------
// Wt[n][k] = bf16(W[k][n]) for n<validN else 0.  Kdim, dstRows multiples of 64.
// 64x64 tile; coalesced f32x4 reads, coalesced 16B bf16 writes.
__global__ __launch_bounds__(256)
void transpose_cast_kernel(const float* __restrict__ W, short* __restrict__ Wt,
                           int srcN, int validN, int Kdim, int nTilesN) {
  __shared__ short lds[64][72];
  int bid = blockIdx.x;
  int k0 = (bid / nTilesN) * 64;
  int n0 = (bid % nTilesN) * 64;
  int tid = threadIdx.x;
  int rr = tid >> 4;           // 0..15
  int cc = (tid & 15) * 4;     // n offset
#pragma unroll
  for (int pass = 0; pass < 4; ++pass) {
    int k = pass * 16 + rr;
    int gn = n0 + cc;
    f32x4 v = (f32x4)0.f;
    if (gn < validN) v = *(const f32x4*)(W + (size_t)(k0 + k) * srcN + gn);
    uint32_t p0 = (uint32_t)(uint16_t)f2bf(v[0]) | ((uint32_t)(uint16_t)f2bf(v[1]) << 16);
    uint32_t p1 = (uint32_t)(uint16_t)f2bf(v[2]) | ((uint32_t)(uint16_t)f2bf(v[3]) << 16);
    *(uint32_t*)&lds[k][cc] = p0;
    *(uint32_t*)&lds[k][cc + 2] = p1;
  }
  __syncthreads();
  int n = tid >> 2;            // 0..63
  int ks = (tid & 3) * 16;     // 0,16,32,48
  short8 a, b;
#pragma unroll
  for (int j = 0; j < 8; ++j) a[j] = lds[ks + j][n];
#pragma unroll
  for (int j = 0; j < 8; ++j) b[j] = lds[ks + 8 + j][n];
  short* dst = Wt + (size_t)(n0 + n) * Kdim + k0 + ks;
  *(short8*)dst = a;
  *(short8*)(dst + 8) = b;
}

// ---------------- dt in f32 (exp-amplified path, exact) ----------------
__global__ __launch_bounds__(256) void dt_kernel(const float* __restrict__ x,
                                                 const float* __restrict__ W_in,
                                                 const float* __restrict__ dt_bias,
                                                 const float* __restrict__ A_log,
                                                 float* __restrict__ dtg,
                                                 float* __restrict__ ldA) {
  int row = blockIdx.x, tid = threadIdx.x;
  float p[NH];
#pragma unroll
  for (int h = 0; h < NH; ++h) p[h] = 0.f;
  for (int k = tid; k < HM; k += 256) {
    float xv = x[(size_t)row * HM + k];
    const float* w = &W_in[(size_t)k * DPROJ + (DPROJ - NH)];
#pragma unroll
    for (int h = 0; h < NH; ++h) p[h] = fmaf(xv, w[h], p[h]);
  }
#pragma unroll
  for (int h = 0; h < NH; ++h)
#pragma unroll
    for (int o = 32; o; o >>= 1) p[h] += __shfl_down(p[h], o);
  __shared__ float red[4][NH];
  int lane = tid & 63, w4 = tid >> 6;
  if (lane == 0)
#pragma unroll
    for (int h = 0; h < NH; ++h) red[w4][h] = p[h];
  __syncthreads();
  if (tid < NH) {
    float s = red[0][tid] + red[1][tid] + red[2][tid] + red[3][tid] + dt_bias[tid];
    float dtv = (s > 20.f) ? s : log1pf(expf(s));
    float A = -expf(A_log[tid]);
    dtg[row * NH + tid] = dtv;
    ldA[row * NH + tid] = dtv * A;
  }
}

// ---------------- bf16 MFMA GEMM, 128x128 tile, BK=64, XCD swizzle ---------
// A [M][K] bf16 row-major, B [N][K] bf16 row-major.
// EPI 1: t=y*rsqrt(1+y^2)->bf16  EPI 2: y+bias+resid->f32  EPI 4: split zb/xbcpre
template <int EPI>
__global__ __launch_bounds__(256)
void gemm_bf16(const short* __restrict__ A, const short* __restrict__ B,
               int K, int nTilesN, int N_out,
               float* __restrict__ Cf, short* __restrict__ Cb,
               const float* __restrict__ bias, const float* __restrict__ resid,
               short* __restrict__ Cb2) {
  __shared__ alignas(16) char lds[32768];
  char* As = lds;
  char* Bs = lds + 16384;
  const int tid = threadIdx.x;
  int bid = blockIdx.x;
  {  // XCD-chunked swizzle (bijective when grid % 8 == 0)
    int nwg = gridDim.x;
    if ((nwg & 7) == 0) bid = (bid & 7) * (nwg >> 3) + (bid >> 3);
  }
  const int m0 = (bid / nTilesN) * 128;
  const int n0 = (bid % nTilesN) * 128;
  const int lane = tid & 63;
  const int wave = tid >> 6;
  const int wr = wave >> 1, wc = wave & 1;
  const int lrow = lane & 15, lk = lane >> 4;

  f32x4 acc[4][4];
#pragma unroll
  for (int i = 0; i < 4; ++i)
#pragma unroll
    for (int j = 0; j < 4; ++j) acc[i][j] = (f32x4)0.f;

  for (int k0 = 0; k0 < K; k0 += 64) {
#pragma unroll
    for (int r = 0; r < 4; ++r) {
      int p = r * 4096 + tid * 16;
      int row = p >> 7, c = p & 127;
      int sc = c ^ ((row & 7) << 4);
      gload_lds16((const char*)A + ((size_t)(m0 + row) * K + k0) * 2 + sc, As + p);
      gload_lds16((const char*)B + ((size_t)(n0 + row) * K + k0) * 2 + sc, Bs + p);
    }
    asm volatile("s_waitcnt vmcnt(0)" ::: "memory");
    __syncthreads();
#pragma unroll
    for (int ks = 0; ks < 2; ++ks) {
      short8 av[4], bv[4];
#pragma unroll
      for (int i = 0; i < 4; ++i) {
        av[i] = fragr(As, wr * 64 + i * 16 + lrow, ks * 64 + lk * 16);
        bv[i] = fragr(Bs, wc * 64 + i * 16 + lrow, ks * 64 + lk * 16);
      }
#pragma unroll
      for (int i = 0; i < 4; ++i)
#pragma unroll
        for (int j = 0; j < 4; ++j)
          acc[i][j] = __builtin_amdgcn_mfma_f32_16x16x32_bf16(av[i], bv[j], acc[i][j], 0, 0, 0);
    }
    __syncthreads();
  }

  const int row0 = m0 + wr * 64, col0 = n0 + wc * 64;
#pragma unroll
  for (int i = 0; i < 4; ++i)
#pragma unroll
    for (int j = 0; j < 4; ++j)
#pragma unroll
      for (int r = 0; r < 4; ++r) {
        int row = row0 + i * 16 + lk * 4 + r;
        int col = col0 + j * 16 + lrow;
        float v = acc[i][j][r];
        if (EPI == 1) {
          float t = v * rsqrtf(1.f + v * v);
          Cb[(size_t)row * N_out + col] = f2bf(t);
        } else if (EPI == 2) {
          Cf[(size_t)row * N_out + col] = v + bias[col] + resid[(size_t)row * N_out + col];
        } else {  // EPI 4: cols<2048 -> zb; 2048..4223 -> xbcpre
          if (col < DINNER) Cb[(size_t)row * DINNER + col] = f2bf(v);
          else if (col < DINNER + CONVD) Cb2[(size_t)row * CONVD + (col - DINNER)] = f2bf(v);
        }
      }
}

// ---------------- depthwise causal conv16 + SiLU, register-blocked ----------
// xbc stores coalesced; xT/bT written via LDS block transpose (full 64B lines)
__global__ __launch_bounds__(256) void conv_silu_kernel(const short* __restrict__ xbcpre,
                                                        const float* __restrict__ cw,
                                                        const float* __restrict__ cbias,
                                                        short* __restrict__ xbc,
                                                        short* __restrict__ xT,
                                                        short* __restrict__ bTg) {
  __shared__ short tld[64][130];   // [t][128 ch + 2 pad]
  int blk = blockIdx.x;            // 17*32*4
  int cg = blk % 17;
  int tg = (blk / 17) % 32;
  int b  = blk / (17 * 32);
  int lane = threadIdx.x & 63;
  int warp = threadIdx.x >> 6;
  int c0 = cg * 128 + lane * 2;
  int tbase = (tg * 4 + warp) * TT;

  const short* inp = xbcpre + (size_t)(b * SEQLEN) * CONVD + c0;
  uint32_t in[TT + DCONV - 1];
#pragma unroll
  for (int j = 0; j < TT + DCONV - 1; ++j) {
    int t = tbase + j - (DCONV - 1);
    in[j] = (t >= 0) ? *(const uint32_t*)(inp + (size_t)t * CONVD) : 0u;
  }
  float w0[DCONV], w1[DCONV];
  const float* wp = cw + (size_t)c0 * DCONV;
#pragma unroll
  for (int k = 0; k < DCONV; ++k) { w0[k] = wp[k]; w1[k] = wp[DCONV + k]; }
  float bb0 = cbias[c0], bb1 = cbias[c0 + 1];

  short* outp = xbc + (size_t)(b * SEQLEN) * CONVD + c0;
#pragma unroll
  for (int tt = 0; tt < TT; ++tt) {
    float a0 = bb0, a1 = bb1;
#pragma unroll
    for (int k = 0; k < DCONV; ++k) {
      uint32_t v = in[tt + k];
      a0 = fmaf(bf2f((short)(v & 0xffffu)), w0[k], a0);
      a1 = fmaf(bf2f((short)(v >> 16)), w1[k], a1);
    }
    a0 = a0 * sigmoidf_fast(a0);
    a1 = a1 * sigmoidf_fast(a1);
    uint32_t o = (uint32_t)(uint16_t)f2bf(a0) | ((uint32_t)(uint16_t)f2bf(a1) << 16);
    *(uint32_t*)(outp + (size_t)(tbase + tt) * CONVD) = o;
    *(uint32_t*)&tld[warp * TT + tt][lane * 2] = o;
  }
  __syncthreads();
  // write xT / bT rows: one full 64B line per thread
  int ch = threadIdx.x & 127;
  int seg = threadIdx.x >> 7;          // 0/1 -> t 0..31 / 32..63
  int gc = cg * 128 + ch;
  short* dst = nullptr;
  if (gc < DINNER) dst = xT + (size_t)gc * ROWS;
  else if (gc < DINNER + NS) dst = bTg + (size_t)(gc - DINNER) * ROWS;
  if (dst) {
    int tcol = b * SEQLEN + tg * 64 + seg * 32;
    short8 v[4];
#pragma unroll
    for (int q = 0; q < 4; ++q)
#pragma unroll
      for (int j = 0; j < 8; ++j) v[q][j] = tld[seg * 32 + q * 8 + j][ch];
    short8* dp = (short8*)(dst + tcol);
    dp[0] = v[0]; dp[1] = v[1]; dp[2] = v[2]; dp[3] = v[3];
  }
}

// ---------------- scan pass A (MFMA): big-chunk state contribution ----------
__global__ __launch_bounds__(256)
void scan_passA_mfma(const short* __restrict__ xT, const short* __restrict__ bTg,
                     const float* __restrict__ dtg, const float* __restrict__ ldA,
                     float* __restrict__ Sg, float* __restrict__ Pg) {
  __shared__ alignas(16) char Ax[32768];   // [256p][64s]
  __shared__ alignas(16) char Bt[8192];    // [64n][64s]
  __shared__ float aa[QC + 1];
  __shared__ float wdt[QC];
  int blk = blockIdx.x;
  int c8 = blk & 7, bh = blk >> 3;
  int h = bh & 7, b = bh >> 3;
  int tid = threadIdx.x, wave = tid >> 6, lane = tid & 63;
  int lrow = lane & 15, lk = lane >> 4;
  int rowbase = b * SEQLEN + c8 * QC;
  if (tid == 0) {
    float s = 0.f; aa[0] = 0.f;
    for (int t = 0; t < QC; ++t) { s += ldA[(rowbase + t) * NH + h]; aa[t + 1] = s; }
    Pg[blk] = __expf(s);
  }
  __syncthreads();
  float alast = aa[QC];
  wdt[tid] = __expf(alast - aa[tid + 1]) * dtg[(rowbase + tid) * NH + h];

  f32x4 acc[4][4];
#pragma unroll
  for (int i = 0; i < 4; ++i)
#pragma unroll
    for (int j = 0; j < 4; ++j) acc[i][j] = (f32x4)0.f;

  for (int ks = 0; ks < 4; ++ks) {
    int s0 = ks * 64;
#pragma unroll
    for (int it = 0; it < 8; ++it) {
      int p = it * 4096 + tid * 16;
      int row = p >> 7, c = p & 127;
      int sc = c ^ ((row & 7) << 4);
      gload_lds16((const char*)(xT + (size_t)(h * HD + row) * ROWS + rowbase + s0) + sc, Ax + p);
    }
#pragma unroll
    for (int it = 0; it < 2; ++it) {
      int p = it * 4096 + tid * 16;
      int row = p >> 7, c = p & 127;
      int sc = c ^ ((row & 7) << 4);
      gload_lds16((const char*)(bTg + (size_t)row * ROWS + rowbase + s0) + sc, Bt + p);
    }
    asm volatile("s_waitcnt vmcnt(0)" ::: "memory");
    __syncthreads();
    {
      int row = tid;
#pragma unroll
      for (int g = 0; g < 8; ++g) {
        int off = row * 128 + g * 16;
        int sb = s0 + (((g * 16) ^ ((row & 7) << 4)) >> 1);
        short8 v = *(short8*)(Ax + off);
        short8 o;
#pragma unroll
        for (int j = 0; j < 8; ++j) o[j] = f2bf(bf2f(v[j]) * wdt[sb + j]);
        *(short8*)(Ax + off) = o;
      }
    }
    __syncthreads();
#pragma unroll
    for (int kk = 0; kk < 2; ++kk) {
      short8 av[4], bv[4];
#pragma unroll
      for (int i = 0; i < 4; ++i) {
        av[i] = fragr(Ax, wave * 64 + i * 16 + lrow, kk * 64 + lk * 16);
        bv[i] = fragr(Bt, i * 16 + lrow, kk * 64 + lk * 16);
      }
#pragma unroll
      for (int i = 0; i < 4; ++i)
#pragma unroll
        for (int j = 0; j < 4; ++j)
          acc[i][j] = __builtin_amdgcn_mfma_f32_16x16x32_bf16(av[i], bv[j], acc[i][j], 0, 0, 0);
    }
    __syncthreads();
  }
#pragma unroll
  for (int i = 0; i < 4; ++i)
#pragma unroll
    for (int j = 0; j < 4; ++j)
#pragma unroll
      for (int r = 0; r < 4; ++r) {
        int p = wave * 64 + i * 16 + lk * 4 + r;
        int n = j * 16 + lrow;
        Sg[((size_t)blk * 256 + p) * 64 + n] = acc[i][j][r];
      }
}

// ---------------- scan pass B: inter-chunk combine ----------
__global__ __launch_bounds__(256)
void scan_passB(const float* __restrict__ Sg, const float* __restrict__ Pg,
                const float* __restrict__ init, float* __restrict__ Hg) {
  int blk = blockIdx.x;
  int ptile = blk & 15, bh = blk >> 4;
  int h = bh & (NH - 1);
  int tid = threadIdx.x;
  size_t off = (size_t)ptile * 1024 + tid * 4;
  f32x4 hc = *(const f32x4*)(init + (size_t)h * HD * NS + off);
#pragma unroll 1
  for (int c = 0; c < NC; ++c) {
    *(f32x4*)(Hg + (size_t)(bh * NC + c) * 16384 + off) = hc;
    float P = Pg[bh * NC + c];
    f32x4 s = *(const f32x4*)(Sg + (size_t)(bh * NC + c) * 16384 + off);
    hc = P * hc + s;
  }
}

// ---------------- scan pass C (MFMA): chunked y computation ----------------
__global__ __launch_bounds__(256)
void scan_passC_mfma(const short* __restrict__ xT, const short* __restrict__ bTg,
                     const short* __restrict__ xbc,
                     const float* __restrict__ dtg, const float* __restrict__ ldA,
                     const float* __restrict__ Hg, const float* __restrict__ Dp,
                     short* __restrict__ yfull) {
  __shared__ alignas(16) char Xb[32768];   // [256p][64s]
  __shared__ alignas(16) char Hb[32768];   // [256p][64n]
  __shared__ alignas(16) char Bn[8192];    // [64s][64n]
  __shared__ alignas(16) char Cn[8192];    // [64t][64n]
  __shared__ alignas(16) char Bt2[8192];   // [64n][64s]
  __shared__ alignas(16) char Mm[8192];    // [64t][64s]
  __shared__ float aa[QC + 1];
  __shared__ float dts[QC];
  int blk = blockIdx.x;
  int c8 = blk & 7, bh = blk >> 3;
  int h = bh & 7, b = bh >> 3;
  int tid = threadIdx.x, wave = tid >> 6, lane = tid & 63;
  int lrow = lane & 15, lk = lane >> 4;
  int rowbase = b * SEQLEN + c8 * QC;
  if (tid == 0) {
    float s = 0.f; aa[0] = 0.f;
    for (int t = 0; t < QC; ++t) { s += ldA[(rowbase + t) * NH + h]; aa[t + 1] = s; }
  }
  dts[tid] = dtg[(rowbase + tid) * NH + h];
  __syncthreads();
  float Dh = Dp[h];

  f32x4 hcc[4][4];
  const float* hp = Hg + (size_t)blk * 16384;
#pragma unroll
  for (int i = 0; i < 4; ++i)
#pragma unroll
    for (int j = 0; j < 4; ++j)
#pragma unroll
      for (int r = 0; r < 4; ++r)
        hcc[i][j][r] = hp[(size_t)(wave * 64 + i * 16 + lk * 4 + r) * 64 + j * 16 + lrow];

  for (int sc = 0; sc < 4; ++sc) {
    int s0 = sc * SC;
#pragma unroll
    for (int i = 0; i < 4; ++i)
#pragma unroll
      for (int j = 0; j < 4; ++j)
#pragma unroll
        for (int r = 0; r < 4; ++r) {
          int p = wave * 64 + i * 16 + lk * 4 + r;
          int n = j * 16 + lrow;
          *(short*)(Hb + p * 128 + ((n * 2) ^ ((p & 7) << 4))) = f2bf(hcc[i][j][r]);
        }
#pragma unroll
    for (int it = 0; it < 8; ++it) {
      int p = it * 4096 + tid * 16;
      int row = p >> 7, c = p & 127;
      int scz = c ^ ((row & 7) << 4);
      gload_lds16((const char*)(xT + (size_t)(h * HD + row) * ROWS + rowbase + s0) + scz, Xb + p);
    }
#pragma unroll
    for (int it = 0; it < 2; ++it) {
      int p = it * 4096 + tid * 16;
      int row = p >> 7, c = p & 127;
      int scz = c ^ ((row & 7) << 4);
      gload_lds16((const char*)(xbc + (size_t)(rowbase + s0 + row) * CONVD + DINNER) + scz, Bn + p);
      gload_lds16((const char*)(xbc + (size_t)(rowbase + s0 + row) * CONVD + DINNER + NS) + scz, Cn + p);
      gload_lds16((const char*)(bTg + (size_t)row * ROWS + rowbase + s0) + scz, Bt2 + p);
    }
    asm volatile("s_waitcnt vmcnt(0)" ::: "memory");
    __syncthreads();  // S1

    f32x4 gcc[4];
#pragma unroll
    for (int j = 0; j < 4; ++j) gcc[j] = (f32x4)0.f;
#pragma unroll
    for (int kk = 0; kk < 2; ++kk) {
      short8 avc = fragr(Cn, wave * 16 + lrow, kk * 64 + lk * 16);
#pragma unroll
      for (int j = 0; j < 4; ++j) {
        short8 bvb = fragr(Bn, j * 16 + lrow, kk * 64 + lk * 16);
        gcc[j] = __builtin_amdgcn_mfma_f32_16x16x32_bf16(avc, bvb, gcc[j], 0, 0, 0);
      }
    }
#pragma unroll
    for (int j = 0; j < 4; ++j)
#pragma unroll
      for (int r = 0; r < 4; ++r) {
        int t = wave * 16 + lk * 4 + r;
        int s = j * 16 + lrow;
        float val = (s <= t) ? gcc[j][r] * __expf(aa[s0 + t + 1] - aa[s0 + s + 1]) * dts[s0 + s]
                             : 0.f;
        *(short*)(Mm + t * 128 + ((s * 2) ^ ((t & 7) << 4))) = f2bf(val);
      }
#pragma unroll
    for (int pass = 0; pass < 2; ++pass) {
      int t = wave * 16 + (lane >> 3) + pass * 8;
      int g = lane & 7;
      int off = t * 128 + g * 16;
      float fac = __expf(aa[s0 + t + 1] - aa[s0]);
      short8 v = *(short8*)(Cn + off);
      short8 o;
#pragma unroll
      for (int j = 0; j < 8; ++j) o[j] = f2bf(bf2f(v[j]) * fac);
      *(short8*)(Cn + off) = o;
    }
    __syncthreads();  // S2

    f32x4 ycc[4][4];
#pragma unroll
    for (int i = 0; i < 4; ++i)
#pragma unroll
      for (int j = 0; j < 4; ++j) ycc[i][j] = (f32x4)0.f;
#pragma unroll
    for (int kk = 0; kk < 2; ++kk) {
      short8 av[4], bv[4];
#pragma unroll
      for (int i = 0; i < 4; ++i) {
        av[i] = fragr(Mm, i * 16 + lrow, kk * 64 + lk * 16);
        bv[i] = fragr(Xb, wave * 64 + i * 16 + lrow, kk * 64 + lk * 16);
      }
#pragma unroll
      for (int i = 0; i < 4; ++i)
#pragma unroll
        for (int j = 0; j < 4; ++j)
          ycc[i][j] = __builtin_amdgcn_mfma_f32_16x16x32_bf16(av[i], bv[j], ycc[i][j], 0, 0, 0);
    }
#pragma unroll
    for (int kk = 0; kk < 2; ++kk) {
      short8 av[4], bv[4];
#pragma unroll
      for (int i = 0; i < 4; ++i) {
        av[i] = fragr(Cn, i * 16 + lrow, kk * 64 + lk * 16);
        bv[i] = fragr(Hb, wave * 64 + i * 16 + lrow, kk * 64 + lk * 16);
      }
#pragma unroll
      for (int i = 0; i < 4; ++i)
#pragma unroll
        for (int j = 0; j < 4; ++j)
          ycc[i][j] = __builtin_amdgcn_mfma_f32_16x16x32_bf16(av[i], bv[j], ycc[i][j], 0, 0, 0);
    }
#pragma unroll
    for (int i = 0; i < 4; ++i)
#pragma unroll
      for (int j = 0; j < 4; ++j)
#pragma unroll
        for (int r = 0; r < 4; ++r) {
          int t = i * 16 + lk * 4 + r;
          int p = wave * 64 + j * 16 + lrow;
          float xv = bf2f(*(const short*)(Xb + p * 128 + ((t * 2) ^ ((p & 7) << 4))));
          yfull[(size_t)(rowbase + s0 + t) * DINNER + h * HD + p] = f2bf(ycc[i][j][r] + Dh * xv);
        }
    {
      int row = tid;
      float aend = aa[s0 + SC];
#pragma unroll
      for (int g = 0; g < 8; ++g) {
        int off = row * 128 + g * 16;
        int sb = s0 + (((g * 16) ^ ((row & 7) << 4)) >> 1);
        short8 v = *(short8*)(Xb + off);
        short8 o;
#pragma unroll
        for (int j = 0; j < 8; ++j)
          o[j] = f2bf(bf2f(v[j]) * __expf(aend - aa[sb + j + 1]) * dts[sb + j]);
        *(short8*)(Xb + off) = o;
      }
    }
    {
      float Ps = __expf(aa[s0 + SC] - aa[s0]);
#pragma unroll
      for (int i = 0; i < 4; ++i)
#pragma unroll
        for (int j = 0; j < 4; ++j) hcc[i][j] *= Ps;
#pragma unroll
      for (int kk = 0; kk < 2; ++kk) {
        short8 av[4], bv[4];
#pragma unroll
        for (int i = 0; i < 4; ++i) {
          av[i] = fragr(Xb, wave * 64 + i * 16 + lrow, kk * 64 + lk * 16);
          bv[i] = fragr(Bt2, i * 16 + lrow, kk * 64 + lk * 16);
        }
#pragma unroll
        for (int i = 0; i < 4; ++i)
#pragma unroll
          for (int j = 0; j < 4; ++j)
            hcc[i][j] = __builtin_amdgcn_mfma_f32_16x16x32_bf16(av[i], bv[j], hcc[i][j], 0, 0, 0);
      }
    }
    __syncthreads();  // S3
  }
}

// ---------------- gate (silu(z)) + RMSNorm -> bf16 ----------------
__global__ __launch_bounds__(256)
void gate_norm_kernel(const short* __restrict__ yfull, const short* __restrict__ zb,
                      const float* __restrict__ norm_w, short* __restrict__ yn) {
  int row = blockIdx.x, tid = threadIdx.x;
  size_t yb = (size_t)row * DINNER;
  float v[8];
  float ss = 0.f;
#pragma unroll
  for (int g = 0; g < 2; ++g) {
    int cidx = g * 1024 + tid * 4;
    short4v y4 = *(const short4v*)(yfull + yb + cidx);
    short4v z4 = *(const short4v*)(zb + yb + cidx);
#pragma unroll
    for (int j = 0; j < 4; ++j) {
      float z = bf2f(z4[j]);
      float val = bf2f(y4[j]) * z * sigmoidf_fast(z);
      v[g * 4 + j] = val;
      ss = fmaf(val, val, ss);
    }
  }
#pragma unroll
  for (int o = 32; o; o >>= 1) ss += __shfl_down(ss, o);
  __shared__ float red[4];
  if ((tid & 63) == 0) red[tid >> 6] = ss;
  __syncthreads();
  float tot = red[0] + red[1] + red[2] + red[3];
  float scale = rsqrtf(tot * (1.f / (float)DINNER) + 1e-5f);
#pragma unroll
  for (int g = 0; g < 2; ++g) {
    int cidx = g * 1024 + tid * 4;
    short4v o4;
#pragma unroll
    for (int j = 0; j < 4; ++j) o4[j] = f2bf(v[g * 4 + j] * scale * norm_w[cidx + j]);
    *(short4v*)(yn + yb + cidx) = o4;
  }
}

// ---------------- launcher ----------------
extern "C" void kernel_launch(void* const* d_in, const int* in_sizes, int n_in,
                              void* d_out, int out_size, void* d_ws, size_t ws_size,
                              hipStream_t stream) {
  (void)in_sizes; (void)n_in; (void)out_size; (void)ws_size;
  const float* x     = (const float*)d_in[0];
  const float* W_in  = (const float*)d_in[1];
  const float* convw = (const float*)d_in[2];
  const float* convb = (const float*)d_in[3];
  const float* dtb   = (const float*)d_in[4];
  const float* Alog  = (const float*)d_in[5];
  const float* Dp    = (const float*)d_in[6];
  const float* inis  = (const float*)d_in[7];
  const float* nw    = (const float*)d_in[8];
  const float* W_out = (const float*)d_in[9];
  const float* W_nl  = (const float*)d_in[10];
  const float* b_nl  = (const float*)d_in[11];
  float* out = (float*)d_out;
  char* ws = (char*)d_ws;

  short* woutT  = (short*)(ws + O_WOUT);
  short* wnlT   = (short*)(ws + O_WNL);
  float* dtg    = (float*)(ws + O_DT);
  float* ldA    = (float*)(ws + O_LDA);
  float* Pg     = (float*)(ws + O_PG);
  short* bTg    = (short*)(ws + O_BT);
  short* zb     = (short*)(ws + O_ZB);
  short* xbcpre = (short*)(ws + O_XBCPRE);
  float* Sg     = (float*)(ws + O_SG);
  float* Hg     = (float*)(ws + O_HG);
  short* tb     = (short*)(ws + O_TB);
  short* xbc    = (short*)(ws + O_XBC);
  short* yn     = (short*)(ws + O_YN);
  short* xT     = (short*)(ws + O_XTR);
  short* xbf    = (short*)(ws + O_XBF);
  short* winT   = (short*)(ws + O_WIN);
  short* yfull  = (short*)d_out;

  cast_x_kernel<<<8192, 256, 0, stream>>>(x, xbf);
  // winT[4352][1024] = W_in^T (pad rows >= 4232 with 0): 16 x 68 tiles
  transpose_cast_kernel<<<16 * 68, 256, 0, stream>>>(W_in, winT, DPROJ, DPROJ, HM, 68);
  // woutT[1024][2048] = W_out^T: 32 x 16 tiles
  transpose_cast_kernel<<<32 * 16, 256, 0, stream>>>(W_out, woutT, HM, HM, DINNER, 16);
  // wnlT[1024][1024] = W_nl^T: 16 x 16 tiles
  transpose_cast_kernel<<<16 * 16, 256, 0, stream>>>(W_nl, wnlT, HM, HM, HM, 16);
  dt_kernel<<<ROWS, 256, 0, stream>>>(x, W_in, dtb, Alog, dtg, ldA);

  gemm_bf16<4><<<64 * 34, 256, 0, stream>>>(xbf, winT, HM, 34, 0, nullptr, zb, nullptr, nullptr, xbcpre);
  conv_silu_kernel<<<17 * 32 * 4, 256, 0, stream>>>(xbcpre, convw, convb, xbc, xT, bTg);

  scan_passA_mfma<<<32 * NC, 256, 0, stream>>>(xT, bTg, dtg, ldA, Sg, Pg);
  scan_passB<<<32 * 16, 256, 0, stream>>>(Sg, Pg, inis, Hg);
  scan_passC_mfma<<<32 * NC, 256, 0, stream>>>(xT, bTg, xbc, dtg, ldA, Hg, Dp, yfull);

  gate_norm_kernel<<<ROWS, 256, 0, stream>>>(yfull, zb, nw, yn);
  gemm_bf16<1><<<64 * 8, 256, 0, stream>>>(yn, woutT, DINNER, 8, HM, nullptr, tb, nullptr, nullptr, nullptr);
  gemm_bf16<2><<<64 * 8, 256, 0, stream>>>(tb, wnlT, HM, 8, HM, out, nullptr, b_nl, x, nullptr);
}

// Round 6
// 396.027 us; speedup vs baseline: 2.7392x; 1.0283x over previous
//
#include <hip/hip_runtime.h>
#include <stdint.h>
#include <stddef.h>

// ---------------- problem dims ----------------
#define BATCH   4
#define SEQLEN  2048
#define HM      1024
#define DINNER  2048
#define NH      8
#define HD      256
#define NS      64
#define CONVD   2176
#define DCONV   16
#define DPROJ   4232
#define ROWS    (BATCH*SEQLEN)  // 8192
#define QC      256             // big-chunk length
#define NC      (SEQLEN/QC)     // 8 big-chunks
#define SC      64              // sub-chunk length (passC)
#define TT      16              // conv timesteps per thread

typedef __attribute__((ext_vector_type(8))) short short8;
typedef __attribute__((ext_vector_type(4))) short short4v;
typedef __attribute__((ext_vector_type(4))) float f32x4;

// ---------------- workspace layout (bytes), peak ~139.5 MiB ----------------
static constexpr size_t O_WOUT   = 0;                    //  4,194,304
static constexpr size_t O_WNL    = 4194304;              //  2,097,152
static constexpr size_t O_DT     = 6291456;              //    262,144
static constexpr size_t O_LDA    = 6553600;              //    262,144
static constexpr size_t O_PG     = 6815744;              //      4,096
static constexpr size_t O_BT     = 6819840;              //  1,048,576
static constexpr size_t O_ZB     = 7868416;              // 33,554,432  bf16 z[8192][2048]
static constexpr size_t O_XBCPRE = 41422848;             // 35,651,584  bf16 [8192][2176]
static constexpr size_t O_SG     = O_XBCPRE;             // 16,777,216  f32 [65536][64]
static constexpr size_t O_HG     = O_XBCPRE + 16777216;  // 16,777,216  f32 [256][16384]
static constexpr size_t O_TB     = O_XBCPRE;             // 16,777,216  bf16 [8192][1024]
static constexpr size_t O_XBC    = 77074432;             // 35,651,584  bf16 [8192][2176]
static constexpr size_t O_YN     = O_XBC;                // 33,554,432  bf16 [8192][2048]
static constexpr size_t O_XTR    = 112726016;            // 33,554,432  bf16 xT[2048][8192]
static constexpr size_t O_XBF    = O_XTR;                // 16,777,216  bf16 [8192][1024]
static constexpr size_t O_WIN    = O_XTR + 16777216;     //  8,912,896  bf16 [4352][1024]
// END = 146,280,448

// ---------------- helpers ----------------
__device__ __forceinline__ short f2bf(float f) {
  union { float f; uint32_t u; } v; v.f = f;
  uint32_t r = v.u + 0x7fffu + ((v.u >> 16) & 1u);
  return (short)(r >> 16);
}

__device__ __forceinline__ float bf2f(short s) {
  union { float f; uint32_t u; } v;
  v.u = ((uint32_t)(uint16_t)s) << 16;
  return v.f;
}

__device__ __forceinline__ void gload_lds16(const void* g, void* l) {
  __builtin_amdgcn_global_load_lds(
      (const __attribute__((address_space(1))) uint32_t*)g,
      (__attribute__((address_space(3))) uint32_t*)l, 16, 0, 0);
}

__device__ __forceinline__ float sigmoidf_fast(float x) {
  return 1.f / (1.f + __expf(-x));
}

// fragment read from a [rows][64-elem] bf16 LDS tile (128B rows, XOR-swizzled)
__device__ __forceinline__ short8 fragr(const char* base, int row, int kbyte) {
  return *(const short8*)(base + row * 128 + (kbyte ^ ((row & 7) << 4)));
}

// ---------------- cast x (row-major, coalesced) ----------------
__global__ __launch_bounds__(256) void cast_x_kernel(const float* __restrict__ x,
                                                     short* __restrict__ xb) {
  int i = blockIdx.x * 256 + threadIdx.x;
  f32x4 v = ((const f32x4*)x)[i];
  short4v o = { f2bf(v[0]), f2bf(v[1]), f2bf(v[2]), f2bf(v[3]) };
  ((short4v*)xb)[i] = o;
}

// ---------------- generic LDS-tiled transpose-cast -------------------------
__global__ __launch_bounds__(256)
void transpose_cast_kernel(const float* __restrict__ W, short* __restrict__ Wt,
                           int srcN, int validN, int Kdim, int nTilesN) {
  __shared__ short lds[64][72];
  int bid = blockIdx.x;
  int k0 = (bid / nTilesN) * 64;
  int n0 = (bid % nTilesN) * 64;
  int tid = threadIdx.x;
  int rr = tid >> 4;
  int cc = (tid & 15) * 4;
#pragma unroll
  for (int pass = 0; pass < 4; ++pass) {
    int k = pass * 16 + rr;
    int gn = n0 + cc;
    f32x4 v = (f32x4)0.f;
    if (gn < validN) v = *(const f32x4*)(W + (size_t)(k0 + k) * srcN + gn);
    uint32_t p0 = (uint32_t)(uint16_t)f2bf(v[0]) | ((uint32_t)(uint16_t)f2bf(v[1]) << 16);
    uint32_t p1 = (uint32_t)(uint16_t)f2bf(v[2]) | ((uint32_t)(uint16_t)f2bf(v[3]) << 16);
    *(uint32_t*)&lds[k][cc] = p0;
    *(uint32_t*)&lds[k][cc + 2] = p1;
  }
  __syncthreads();
  int n = tid >> 2;
  int ks = (tid & 3) * 16;
  short8 a, b;
#pragma unroll
  for (int j = 0; j < 8; ++j) a[j] = lds[ks + j][n];
#pragma unroll
  for (int j = 0; j < 8; ++j) b[j] = lds[ks + 8 + j][n];
  short* dst = Wt + (size_t)(n0 + n) * Kdim + k0 + ks;
  *(short8*)dst = a;
  *(short8*)(dst + 8) = b;
}

// ---------------- dt in f32 (exp-amplified path, exact) ----------------
__global__ __launch_bounds__(256) void dt_kernel(const float* __restrict__ x,
                                                 const float* __restrict__ W_in,
                                                 const float* __restrict__ dt_bias,
                                                 const float* __restrict__ A_log,
                                                 float* __restrict__ dtg,
                                                 float* __restrict__ ldA) {
  int row = blockIdx.x, tid = threadIdx.x;
  float p[NH];
#pragma unroll
  for (int h = 0; h < NH; ++h) p[h] = 0.f;
  for (int k = tid; k < HM; k += 256) {
    float xv = x[(size_t)row * HM + k];
    const float* w = &W_in[(size_t)k * DPROJ + (DPROJ - NH)];
#pragma unroll
    for (int h = 0; h < NH; ++h) p[h] = fmaf(xv, w[h], p[h]);
  }
#pragma unroll
  for (int h = 0; h < NH; ++h)
#pragma unroll
    for (int o = 32; o; o >>= 1) p[h] += __shfl_down(p[h], o);
  __shared__ float red[4][NH];
  int lane = tid & 63, w4 = tid >> 6;
  if (lane == 0)
#pragma unroll
    for (int h = 0; h < NH; ++h) red[w4][h] = p[h];
  __syncthreads();
  if (tid < NH) {
    float s = red[0][tid] + red[1][tid] + red[2][tid] + red[3][tid] + dt_bias[tid];
    float dtv = (s > 20.f) ? s : log1pf(expf(s));
    float A = -expf(A_log[tid]);
    dtg[row * NH + tid] = dtv;
    ldA[row * NH + tid] = dtv * A;
  }
}

// ---------------- 8-wave 256x128 deep-pipelined bf16 GEMM ------------------
// A [M][K] bf16 row-major, B [N][K] bf16 row-major. K % 128 == 0.
// Ring of 3 LDS slots (one BK=64 K-tile each: A 32KB + B 16KB); compute kt
// from slot kt%3 while staging kt+2 into slot (kt+2)%3 (== (kt-1)%3, consumed).
// 4 phases/K-tile, counted vmcnt(6), raw barriers, setprio around MFMA.
// EPI 1: t=y*rsqrt(1+y^2)->bf16  EPI 2: y+bias+resid->f32  EPI 4: split zb/xbcpre
template <int EPI>
__global__ __launch_bounds__(512)
void gemm8p(const short* __restrict__ A, const short* __restrict__ B,
            int K, int nTilesN, int N_out,
            float* __restrict__ Cf, short* __restrict__ Cb,
            const float* __restrict__ bias, const float* __restrict__ resid,
            short* __restrict__ Cb2) {
  __shared__ alignas(16) char lds[147456];  // 3 slots x 48KB
  const int tid = threadIdx.x;
  int bid = blockIdx.x;
  {  // XCD-chunked swizzle (all grids % 8 == 0)
    int nwg = gridDim.x;
    if ((nwg & 7) == 0) bid = (bid & 7) * (nwg >> 3) + (bid >> 3);
  }
  const int m0 = (bid / nTilesN) * 256;
  const int n0 = (bid % nTilesN) * 128;
  const int lane = tid & 63;
  const int wid = tid >> 6;          // 8 waves
  const int wm = wid >> 1;           // 0..3 -> rows wm*64
  const int wn = wid & 1;            // 0..1 -> cols wn*64
  const int lrow = lane & 15, lk = lane >> 4;
  const int nK = K >> 6;

#define LDSA(s) (lds + (s) * 49152)
#define LDSB(s) (lds + (s) * 49152 + 32768)

#define STAGE_A(s, kt, it) do {                                              \
    int p_ = (it) * 8192 + tid * 16;                                         \
    int row_ = p_ >> 7, c_ = p_ & 127;                                       \
    int sc_ = c_ ^ ((row_ & 7) << 4);                                        \
    gload_lds16((const char*)A + ((size_t)(m0 + row_) * K + (kt) * 64) * 2 + sc_, \
                LDSA(s) + p_);                                               \
  } while (0)
#define STAGE_B(s, kt, it) do {                                              \
    int p_ = (it) * 8192 + tid * 16;                                         \
    int row_ = p_ >> 7, c_ = p_ & 127;                                       \
    int sc_ = c_ ^ ((row_ & 7) << 4);                                        \
    gload_lds16((const char*)B + ((size_t)(n0 + row_) * K + (kt) * 64) * 2 + sc_, \
                LDSB(s) + p_);                                               \
  } while (0)

  f32x4 acc[4][4];
#pragma unroll
  for (int i = 0; i < 4; ++i)
#pragma unroll
    for (int j = 0; j < 4; ++j) acc[i][j] = (f32x4)0.f;

  // prologue: stage kt=0 -> slot0, kt=1 -> slot1; wait kt0 (leave kt1 in flight)
#pragma unroll
  for (int it = 0; it < 4; ++it) STAGE_A(0, 0, it);
#pragma unroll
  for (int it = 0; it < 2; ++it) STAGE_B(0, 0, it);
#pragma unroll
  for (int it = 0; it < 4; ++it) STAGE_A(1, 1, it);
#pragma unroll
  for (int it = 0; it < 2; ++it) STAGE_B(1, 1, it);
  asm volatile("s_waitcnt vmcnt(6)" ::: "memory");
  __builtin_amdgcn_s_barrier();

  for (int kt = 0; kt < nK; ++kt) {
    const int rs = kt % 3;
    const int ss = (kt + 2) % 3;
    const bool st = (kt + 2) < nK;
    const char* Ab = LDSA(rs);
    const char* Bb = LDSB(rs);
    short8 aLo[2][2], aHi[2][2], bj[4][2];

    // ---- phase 1: read A(i0,i1)+B(j0,j1); stage A it0,it1 of kt+2
#pragma unroll
    for (int ii = 0; ii < 2; ++ii)
#pragma unroll
      for (int ks = 0; ks < 2; ++ks)
        aLo[ii][ks] = fragr(Ab, wm * 64 + ii * 16 + lrow, ks * 64 + lk * 16);
#pragma unroll
    for (int jj = 0; jj < 2; ++jj)
#pragma unroll
      for (int ks = 0; ks < 2; ++ks)
        bj[jj][ks] = fragr(Bb, wn * 64 + jj * 16 + lrow, ks * 64 + lk * 16);
    if (st) { STAGE_A(ss, kt + 2, 0); STAGE_A(ss, kt + 2, 1); }
    __builtin_amdgcn_s_barrier();
    asm volatile("s_waitcnt lgkmcnt(0)" ::: "memory");
    __builtin_amdgcn_s_setprio(1);
#pragma unroll
    for (int ii = 0; ii < 2; ++ii)
#pragma unroll
      for (int jj = 0; jj < 2; ++jj)
#pragma unroll
        for (int ks = 0; ks < 2; ++ks)
          acc[ii][jj] = __builtin_amdgcn_mfma_f32_16x16x32_bf16(aLo[ii][ks], bj[jj][ks], acc[ii][jj], 0, 0, 0);
    __builtin_amdgcn_s_setprio(0);
    __builtin_amdgcn_s_barrier();

    // ---- phase 2: read B(j2,j3); stage A it2,it3
#pragma unroll
    for (int jj = 2; jj < 4; ++jj)
#pragma unroll
      for (int ks = 0; ks < 2; ++ks)
        bj[jj][ks] = fragr(Bb, wn * 64 + jj * 16 + lrow, ks * 64 + lk * 16);
    if (st) { STAGE_A(ss, kt + 2, 2); STAGE_A(ss, kt + 2, 3); }
    __builtin_amdgcn_s_barrier();
    asm volatile("s_waitcnt lgkmcnt(0)" ::: "memory");
    __builtin_amdgcn_s_setprio(1);
#pragma unroll
    for (int ii = 0; ii < 2; ++ii)
#pragma unroll
      for (int jj = 2; jj < 4; ++jj)
#pragma unroll
        for (int ks = 0; ks < 2; ++ks)
          acc[ii][jj] = __builtin_amdgcn_mfma_f32_16x16x32_bf16(aLo[ii][ks], bj[jj][ks], acc[ii][jj], 0, 0, 0);
    __builtin_amdgcn_s_setprio(0);
    __builtin_amdgcn_s_barrier();

    // ---- phase 3: read A(i2,i3); stage B it0
#pragma unroll
    for (int ii = 0; ii < 2; ++ii)
#pragma unroll
      for (int ks = 0; ks < 2; ++ks)
        aHi[ii][ks] = fragr(Ab, wm * 64 + (ii + 2) * 16 + lrow, ks * 64 + lk * 16);
    if (st) STAGE_B(ss, kt + 2, 0);
    __builtin_amdgcn_s_barrier();
    asm volatile("s_waitcnt lgkmcnt(0)" ::: "memory");
    __builtin_amdgcn_s_setprio(1);
#pragma unroll
    for (int ii = 0; ii < 2; ++ii)
#pragma unroll
      for (int jj = 0; jj < 2; ++jj)
#pragma unroll
        for (int ks = 0; ks < 2; ++ks)
          acc[ii + 2][jj] = __builtin_amdgcn_mfma_f32_16x16x32_bf16(aHi[ii][ks], bj[jj][ks], acc[ii + 2][jj], 0, 0, 0);
    __builtin_amdgcn_s_setprio(0);
    __builtin_amdgcn_s_barrier();

    // ---- phase 4: no reads; stage B it1; vmcnt gate at end
    if (st) STAGE_B(ss, kt + 2, 1);
    __builtin_amdgcn_s_barrier();
    __builtin_amdgcn_s_setprio(1);
#pragma unroll
    for (int ii = 0; ii < 2; ++ii)
#pragma unroll
      for (int jj = 2; jj < 4; ++jj)
#pragma unroll
        for (int ks = 0; ks < 2; ++ks)
          acc[ii + 2][jj] = __builtin_amdgcn_mfma_f32_16x16x32_bf16(aHi[ii][ks], bj[jj][ks], acc[ii + 2][jj], 0, 0, 0);
    __builtin_amdgcn_s_setprio(0);
    if (kt >= nK - 2) {
      asm volatile("s_waitcnt vmcnt(0)" ::: "memory");
    } else {
      asm volatile("s_waitcnt vmcnt(6)" ::: "memory");
    }
    __builtin_amdgcn_s_barrier();
  }

  const int row0 = m0 + wm * 64, col0 = n0 + wn * 64;
#pragma unroll
  for (int i = 0; i < 4; ++i)
#pragma unroll
    for (int j = 0; j < 4; ++j)
#pragma unroll
      for (int r = 0; r < 4; ++r) {
        int row = row0 + i * 16 + lk * 4 + r;
        int col = col0 + j * 16 + lrow;
        float v = acc[i][j][r];
        if (EPI == 1) {
          float t = v * rsqrtf(1.f + v * v);
          Cb[(size_t)row * N_out + col] = f2bf(t);
        } else if (EPI == 2) {
          Cf[(size_t)row * N_out + col] = v + bias[col] + resid[(size_t)row * N_out + col];
        } else {  // EPI 4: cols<2048 -> zb; 2048..4223 -> xbcpre
          if (col < DINNER) Cb[(size_t)row * DINNER + col] = f2bf(v);
          else if (col < DINNER + CONVD) Cb2[(size_t)row * CONVD + (col - DINNER)] = f2bf(v);
        }
      }
#undef LDSA
#undef LDSB
#undef STAGE_A
#undef STAGE_B
}

// ---------------- depthwise causal conv16 + SiLU, register-blocked ----------
__global__ __launch_bounds__(256) void conv_silu_kernel(const short* __restrict__ xbcpre,
                                                        const float* __restrict__ cw,
                                                        const float* __restrict__ cbias,
                                                        short* __restrict__ xbc,
                                                        short* __restrict__ xT,
                                                        short* __restrict__ bTg) {
  __shared__ short tld[64][130];   // [t][128 ch + 2 pad]
  int blk = blockIdx.x;            // 17*32*4
  int cg = blk % 17;
  int tg = (blk / 17) % 32;
  int b  = blk / (17 * 32);
  int lane = threadIdx.x & 63;
  int warp = threadIdx.x >> 6;
  int c0 = cg * 128 + lane * 2;
  int tbase = (tg * 4 + warp) * TT;

  const short* inp = xbcpre + (size_t)(b * SEQLEN) * CONVD + c0;
  uint32_t in[TT + DCONV - 1];
#pragma unroll
  for (int j = 0; j < TT + DCONV - 1; ++j) {
    int t = tbase + j - (DCONV - 1);
    in[j] = (t >= 0) ? *(const uint32_t*)(inp + (size_t)t * CONVD) : 0u;
  }
  float w0[DCONV], w1[DCONV];
  const float* wp = cw + (size_t)c0 * DCONV;
#pragma unroll
  for (int k = 0; k < DCONV; ++k) { w0[k] = wp[k]; w1[k] = wp[DCONV + k]; }
  float bb0 = cbias[c0], bb1 = cbias[c0 + 1];

  short* outp = xbc + (size_t)(b * SEQLEN) * CONVD + c0;
#pragma unroll
  for (int tt = 0; tt < TT; ++tt) {
    float a0 = bb0, a1 = bb1;
#pragma unroll
    for (int k = 0; k < DCONV; ++k) {
      uint32_t v = in[tt + k];
      a0 = fmaf(bf2f((short)(v & 0xffffu)), w0[k], a0);
      a1 = fmaf(bf2f((short)(v >> 16)), w1[k], a1);
    }
    a0 = a0 * sigmoidf_fast(a0);
    a1 = a1 * sigmoidf_fast(a1);
    uint32_t o = (uint32_t)(uint16_t)f2bf(a0) | ((uint32_t)(uint16_t)f2bf(a1) << 16);
    *(uint32_t*)(outp + (size_t)(tbase + tt) * CONVD) = o;
    *(uint32_t*)&tld[warp * TT + tt][lane * 2] = o;
  }
  __syncthreads();
  int ch = threadIdx.x & 127;
  int seg = threadIdx.x >> 7;
  int gc = cg * 128 + ch;
  short* dst = nullptr;
  if (gc < DINNER) dst = xT + (size_t)gc * ROWS;
  else if (gc < DINNER + NS) dst = bTg + (size_t)(gc - DINNER) * ROWS;
  if (dst) {
    int tcol = b * SEQLEN + tg * 64 + seg * 32;
    short8 v[4];
#pragma unroll
    for (int q = 0; q < 4; ++q)
#pragma unroll
      for (int j = 0; j < 8; ++j) v[q][j] = tld[seg * 32 + q * 8 + j][ch];
    short8* dp = (short8*)(dst + tcol);
    dp[0] = v[0]; dp[1] = v[1]; dp[2] = v[2]; dp[3] = v[3];
  }
}

// ---------------- scan pass A (MFMA): big-chunk state contribution ----------
__global__ __launch_bounds__(256)
void scan_passA_mfma(const short* __restrict__ xT, const short* __restrict__ bTg,
                     const float* __restrict__ dtg, const float* __restrict__ ldA,
                     float* __restrict__ Sg, float* __restrict__ Pg) {
  __shared__ alignas(16) char Ax[32768];   // [256p][64s]
  __shared__ alignas(16) char Bt[8192];    // [64n][64s]
  __shared__ float aa[QC + 1];
  __shared__ float wdt[QC];
  int blk = blockIdx.x;
  int c8 = blk & 7, bh = blk >> 3;
  int h = bh & 7, b = bh >> 3;
  int tid = threadIdx.x, wave = tid >> 6, lane = tid & 63;
  int lrow = lane & 15, lk = lane >> 4;
  int rowbase = b * SEQLEN + c8 * QC;
  if (tid == 0) {
    float s = 0.f; aa[0] = 0.f;
    for (int t = 0; t < QC; ++t) { s += ldA[(rowbase + t) * NH + h]; aa[t + 1] = s; }
    Pg[blk] = __expf(s);
  }
  __syncthreads();
  float alast = aa[QC];
  wdt[tid] = __expf(alast - aa[tid + 1]) * dtg[(rowbase + tid) * NH + h];

  f32x4 acc[4][4];
#pragma unroll
  for (int i = 0; i < 4; ++i)
#pragma unroll
    for (int j = 0; j < 4; ++j) acc[i][j] = (f32x4)0.f;

  for (int ks = 0; ks < 4; ++ks) {
    int s0 = ks * 64;
#pragma unroll
    for (int it = 0; it < 8; ++it) {
      int p = it * 4096 + tid * 16;
      int row = p >> 7, c = p & 127;
      int sc = c ^ ((row & 7) << 4);
      gload_lds16((const char*)(xT + (size_t)(h * HD + row) * ROWS + rowbase + s0) + sc, Ax + p);
    }
#pragma unroll
    for (int it = 0; it < 2; ++it) {
      int p = it * 4096 + tid * 16;
      int row = p >> 7, c = p & 127;
      int sc = c ^ ((row & 7) << 4);
      gload_lds16((const char*)(bTg + (size_t)row * ROWS + rowbase + s0) + sc, Bt + p);
    }
    asm volatile("s_waitcnt vmcnt(0)" ::: "memory");
    __syncthreads();
    {
      int row = tid;
#pragma unroll
      for (int g = 0; g < 8; ++g) {
        int off = row * 128 + g * 16;
        int sb = s0 + (((g * 16) ^ ((row & 7) << 4)) >> 1);
        short8 v = *(short8*)(Ax + off);
        short8 o;
#pragma unroll
        for (int j = 0; j < 8; ++j) o[j] = f2bf(bf2f(v[j]) * wdt[sb + j]);
        *(short8*)(Ax + off) = o;
      }
    }
    __syncthreads();
#pragma unroll
    for (int kk = 0; kk < 2; ++kk) {
      short8 av[4], bv[4];
#pragma unroll
      for (int i = 0; i < 4; ++i) {
        av[i] = fragr(Ax, wave * 64 + i * 16 + lrow, kk * 64 + lk * 16);
        bv[i] = fragr(Bt, i * 16 + lrow, kk * 64 + lk * 16);
      }
#pragma unroll
      for (int i = 0; i < 4; ++i)
#pragma unroll
        for (int j = 0; j < 4; ++j)
          acc[i][j] = __builtin_amdgcn_mfma_f32_16x16x32_bf16(av[i], bv[j], acc[i][j], 0, 0, 0);
    }
    __syncthreads();
  }
#pragma unroll
  for (int i = 0; i < 4; ++i)
#pragma unroll
    for (int j = 0; j < 4; ++j)
#pragma unroll
      for (int r = 0; r < 4; ++r) {
        int p = wave * 64 + i * 16 + lk * 4 + r;
        int n = j * 16 + lrow;
        Sg[((size_t)blk * 256 + p) * 64 + n] = acc[i][j][r];
      }
}

// ---------------- scan pass B: inter-chunk combine ----------
__global__ __launch_bounds__(256)
void scan_passB(const float* __restrict__ Sg, const float* __restrict__ Pg,
                const float* __restrict__ init, float* __restrict__ Hg) {
  int blk = blockIdx.x;
  int ptile = blk & 15, bh = blk >> 4;
  int h = bh & (NH - 1);
  int tid = threadIdx.x;
  size_t off = (size_t)ptile * 1024 + tid * 4;
  f32x4 hc = *(const f32x4*)(init + (size_t)h * HD * NS + off);
#pragma unroll 1
  for (int c = 0; c < NC; ++c) {
    *(f32x4*)(Hg + (size_t)(bh * NC + c) * 16384 + off) = hc;
    float P = Pg[bh * NC + c];
    f32x4 s = *(const f32x4*)(Sg + (size_t)(bh * NC + c) * 16384 + off);
    hc = P * hc + s;
  }
}

// ---------------- scan pass C (MFMA): chunked y computation ----------------
__global__ __launch_bounds__(256)
void scan_passC_mfma(const short* __restrict__ xT, const short* __restrict__ bTg,
                     const short* __restrict__ xbc,
                     const float* __restrict__ dtg, const float* __restrict__ ldA,
                     const float* __restrict__ Hg, const float* __restrict__ Dp,
                     short* __restrict__ yfull) {
  __shared__ alignas(16) char Xb[32768];   // [256p][64s]
  __shared__ alignas(16) char Hb[32768];   // [256p][64n]
  __shared__ alignas(16) char Bn[8192];    // [64s][64n]
  __shared__ alignas(16) char Cn[8192];    // [64t][64n]
  __shared__ alignas(16) char Bt2[8192];   // [64n][64s]
  __shared__ alignas(16) char Mm[8192];    // [64t][64s]
  __shared__ float aa[QC + 1];
  __shared__ float dts[QC];
  int blk = blockIdx.x;
  int c8 = blk & 7, bh = blk >> 3;
  int h = bh & 7, b = bh >> 3;
  int tid = threadIdx.x, wave = tid >> 6, lane = tid & 63;
  int lrow = lane & 15, lk = lane >> 4;
  int rowbase = b * SEQLEN + c8 * QC;
  if (tid == 0) {
    float s = 0.f; aa[0] = 0.f;
    for (int t = 0; t < QC; ++t) { s += ldA[(rowbase + t) * NH + h]; aa[t + 1] = s; }
  }
  dts[tid] = dtg[(rowbase + tid) * NH + h];
  __syncthreads();
  float Dh = Dp[h];

  f32x4 hcc[4][4];
  const float* hp = Hg + (size_t)blk * 16384;
#pragma unroll
  for (int i = 0; i < 4; ++i)
#pragma unroll
    for (int j = 0; j < 4; ++j)
#pragma unroll
      for (int r = 0; r < 4; ++r)
        hcc[i][j][r] = hp[(size_t)(wave * 64 + i * 16 + lk * 4 + r) * 64 + j * 16 + lrow];

  for (int sc = 0; sc < 4; ++sc) {
    int s0 = sc * SC;
#pragma unroll
    for (int i = 0; i < 4; ++i)
#pragma unroll
      for (int j = 0; j < 4; ++j)
#pragma unroll
        for (int r = 0; r < 4; ++r) {
          int p = wave * 64 + i * 16 + lk * 4 + r;
          int n = j * 16 + lrow;
          *(short*)(Hb + p * 128 + ((n * 2) ^ ((p & 7) << 4))) = f2bf(hcc[i][j][r]);
        }
#pragma unroll
    for (int it = 0; it < 8; ++it) {
      int p = it * 4096 + tid * 16;
      int row = p >> 7, c = p & 127;
      int scz = c ^ ((row & 7) << 4);
      gload_lds16((const char*)(xT + (size_t)(h * HD + row) * ROWS + rowbase + s0) + scz, Xb + p);
    }
#pragma unroll
    for (int it = 0; it < 2; ++it) {
      int p = it * 4096 + tid * 16;
      int row = p >> 7, c = p & 127;
      int scz = c ^ ((row & 7) << 4);
      gload_lds16((const char*)(xbc + (size_t)(rowbase + s0 + row) * CONVD + DINNER) + scz, Bn + p);
      gload_lds16((const char*)(xbc + (size_t)(rowbase + s0 + row) * CONVD + DINNER + NS) + scz, Cn + p);
      gload_lds16((const char*)(bTg + (size_t)row * ROWS + rowbase + s0) + scz, Bt2 + p);
    }
    asm volatile("s_waitcnt vmcnt(0)" ::: "memory");
    __syncthreads();  // S1

    f32x4 gcc[4];
#pragma unroll
    for (int j = 0; j < 4; ++j) gcc[j] = (f32x4)0.f;
#pragma unroll
    for (int kk = 0; kk < 2; ++kk) {
      short8 avc = fragr(Cn, wave * 16 + lrow, kk * 64 + lk * 16);
#pragma unroll
      for (int j = 0; j < 4; ++j) {
        short8 bvb = fragr(Bn, j * 16 + lrow, kk * 64 + lk * 16);
        gcc[j] = __builtin_amdgcn_mfma_f32_16x16x32_bf16(avc, bvb, gcc[j], 0, 0, 0);
      }
    }
#pragma unroll
    for (int j = 0; j < 4; ++j)
#pragma unroll
      for (int r = 0; r < 4; ++r) {
        int t = wave * 16 + lk * 4 + r;
        int s = j * 16 + lrow;
        float val = (s <= t) ? gcc[j][r] * __expf(aa[s0 + t + 1] - aa[s0 + s + 1]) * dts[s0 + s]
                             : 0.f;
        *(short*)(Mm + t * 128 + ((s * 2) ^ ((t & 7) << 4))) = f2bf(val);
      }
#pragma unroll
    for (int pass = 0; pass < 2; ++pass) {
      int t = wave * 16 + (lane >> 3) + pass * 8;
      int g = lane & 7;
      int off = t * 128 + g * 16;
      float fac = __expf(aa[s0 + t + 1] - aa[s0]);
      short8 v = *(short8*)(Cn + off);
      short8 o;
#pragma unroll
      for (int j = 0; j < 8; ++j) o[j] = f2bf(bf2f(v[j]) * fac);
      *(short8*)(Cn + off) = o;
    }
    __syncthreads();  // S2

    f32x4 ycc[4][4];
#pragma unroll
    for (int i = 0; i < 4; ++i)
#pragma unroll
      for (int j = 0; j < 4; ++j) ycc[i][j] = (f32x4)0.f;
#pragma unroll
    for (int kk = 0; kk < 2; ++kk) {
      short8 av[4], bv[4];
#pragma unroll
      for (int i = 0; i < 4; ++i) {
        av[i] = fragr(Mm, i * 16 + lrow, kk * 64 + lk * 16);
        bv[i] = fragr(Xb, wave * 64 + i * 16 + lrow, kk * 64 + lk * 16);
      }
#pragma unroll
      for (int i = 0; i < 4; ++i)
#pragma unroll
        for (int j = 0; j < 4; ++j)
          ycc[i][j] = __builtin_amdgcn_mfma_f32_16x16x32_bf16(av[i], bv[j], ycc[i][j], 0, 0, 0);
    }
#pragma unroll
    for (int kk = 0; kk < 2; ++kk) {
      short8 av[4], bv[4];
#pragma unroll
      for (int i = 0; i < 4; ++i) {
        av[i] = fragr(Cn, i * 16 + lrow, kk * 64 + lk * 16);
        bv[i] = fragr(Hb, wave * 64 + i * 16 + lrow, kk * 64 + lk * 16);
      }
#pragma unroll
      for (int i = 0; i < 4; ++i)
#pragma unroll
        for (int j = 0; j < 4; ++j)
          ycc[i][j] = __builtin_amdgcn_mfma_f32_16x16x32_bf16(av[i], bv[j], ycc[i][j], 0, 0, 0);
    }
#pragma unroll
    for (int i = 0; i < 4; ++i)
#pragma unroll
      for (int j = 0; j < 4; ++j)
#pragma unroll
        for (int r = 0; r < 4; ++r) {
          int t = i * 16 + lk * 4 + r;
          int p = wave * 64 + j * 16 + lrow;
          float xv = bf2f(*(const short*)(Xb + p * 128 + ((t * 2) ^ ((p & 7) << 4))));
          yfull[(size_t)(rowbase + s0 + t) * DINNER + h * HD + p] = f2bf(ycc[i][j][r] + Dh * xv);
        }
    {
      int row = tid;
      float aend = aa[s0 + SC];
#pragma unroll
      for (int g = 0; g < 8; ++g) {
        int off = row * 128 + g * 16;
        int sb = s0 + (((g * 16) ^ ((row & 7) << 4)) >> 1);
        short8 v = *(short8*)(Xb + off);
        short8 o;
#pragma unroll
        for (int j = 0; j < 8; ++j)
          o[j] = f2bf(bf2f(v[j]) * __expf(aend - aa[sb + j + 1]) * dts[sb + j]);
        *(short8*)(Xb + off) = o;
      }
    }
    {
      float Ps = __expf(aa[s0 + SC] - aa[s0]);
#pragma unroll
      for (int i = 0; i < 4; ++i)
#pragma unroll
        for (int j = 0; j < 4; ++j) hcc[i][j] *= Ps;
#pragma unroll
      for (int kk = 0; kk < 2; ++kk) {
        short8 av[4], bv[4];
#pragma unroll
        for (int i = 0; i < 4; ++i) {
          av[i] = fragr(Xb, wave * 64 + i * 16 + lrow, kk * 64 + lk * 16);
          bv[i] = fragr(Bt2, i * 16 + lrow, kk * 64 + lk * 16);
        }
#pragma unroll
        for (int i = 0; i < 4; ++i)
#pragma unroll
          for (int j = 0; j < 4; ++j)
            hcc[i][j] = __builtin_amdgcn_mfma_f32_16x16x32_bf16(av[i], bv[j], hcc[i][j], 0, 0, 0);
      }
    }
    __syncthreads();  // S3
  }
}

// ---------------- gate (silu(z)) + RMSNorm -> bf16 ----------------
__global__ __launch_bounds__(256)
void gate_norm_kernel(const short* __restrict__ yfull, const short* __restrict__ zb,
                      const float* __restrict__ norm_w, short* __restrict__ yn) {
  int row = blockIdx.x, tid = threadIdx.x;
  size_t yb = (size_t)row * DINNER;
  float v[8];
  float ss = 0.f;
#pragma unroll
  for (int g = 0; g < 2; ++g) {
    int cidx = g * 1024 + tid * 4;
    short4v y4 = *(const short4v*)(yfull + yb + cidx);
    short4v z4 = *(const short4v*)(zb + yb + cidx);
#pragma unroll
    for (int j = 0; j < 4; ++j) {
      float z = bf2f(z4[j]);
      float val = bf2f(y4[j]) * z * sigmoidf_fast(z);
      v[g * 4 + j] = val;
      ss = fmaf(val, val, ss);
    }
  }
#pragma unroll
  for (int o = 32; o; o >>= 1) ss += __shfl_down(ss, o);
  __shared__ float red[4];
  if ((tid & 63) == 0) red[tid >> 6] = ss;
  __syncthreads();
  float tot = red[0] + red[1] + red[2] + red[3];
  float scale = rsqrtf(tot * (1.f / (float)DINNER) + 1e-5f);
#pragma unroll
  for (int g = 0; g < 2; ++g) {
    int cidx = g * 1024 + tid * 4;
    short4v o4;
#pragma unroll
    for (int j = 0; j < 4; ++j) o4[j] = f2bf(v[g * 4 + j] * scale * norm_w[cidx + j]);
    *(short4v*)(yn + yb + cidx) = o4;
  }
}

// ---------------- launcher ----------------
extern "C" void kernel_launch(void* const* d_in, const int* in_sizes, int n_in,
                              void* d_out, int out_size, void* d_ws, size_t ws_size,
                              hipStream_t stream) {
  (void)in_sizes; (void)n_in; (void)out_size; (void)ws_size;
  const float* x     = (const float*)d_in[0];
  const float* W_in  = (const float*)d_in[1];
  const float* convw = (const float*)d_in[2];
  const float* convb = (const float*)d_in[3];
  const float* dtb   = (const float*)d_in[4];
  const float* Alog  = (const float*)d_in[5];
  const float* Dp    = (const float*)d_in[6];
  const float* inis  = (const float*)d_in[7];
  const float* nw    = (const float*)d_in[8];
  const float* W_out = (const float*)d_in[9];
  const float* W_nl  = (const float*)d_in[10];
  const float* b_nl  = (const float*)d_in[11];
  float* out = (float*)d_out;
  char* ws = (char*)d_ws;

  short* woutT  = (short*)(ws + O_WOUT);
  short* wnlT   = (short*)(ws + O_WNL);
  float* dtg    = (float*)(ws + O_DT);
  float* ldA    = (float*)(ws + O_LDA);
  float* Pg     = (float*)(ws + O_PG);
  short* bTg    = (short*)(ws + O_BT);
  short* zb     = (short*)(ws + O_ZB);
  short* xbcpre = (short*)(ws + O_XBCPRE);
  float* Sg     = (float*)(ws + O_SG);
  float* Hg     = (float*)(ws + O_HG);
  short* tb     = (short*)(ws + O_TB);
  short* xbc    = (short*)(ws + O_XBC);
  short* yn     = (short*)(ws + O_YN);
  short* xT     = (short*)(ws + O_XTR);
  short* xbf    = (short*)(ws + O_XBF);
  short* winT   = (short*)(ws + O_WIN);
  short* yfull  = (short*)d_out;

  cast_x_kernel<<<8192, 256, 0, stream>>>(x, xbf);
  transpose_cast_kernel<<<16 * 68, 256, 0, stream>>>(W_in, winT, DPROJ, DPROJ, HM, 68);
  transpose_cast_kernel<<<32 * 16, 256, 0, stream>>>(W_out, woutT, HM, HM, DINNER, 16);
  transpose_cast_kernel<<<16 * 16, 256, 0, stream>>>(W_nl, wnlT, HM, HM, HM, 16);
  dt_kernel<<<ROWS, 256, 0, stream>>>(x, W_in, dtb, Alog, dtg, ldA);

  // GEMM1: M=8192, N=4352 (34 tiles of 128), K=1024 -> 32x34 = 1088 blocks
  gemm8p<4><<<32 * 34, 512, 0, stream>>>(xbf, winT, HM, 34, 0, nullptr, zb, nullptr, nullptr, xbcpre);
  conv_silu_kernel<<<17 * 32 * 4, 256, 0, stream>>>(xbcpre, convw, convb, xbc, xT, bTg);

  scan_passA_mfma<<<32 * NC, 256, 0, stream>>>(xT, bTg, dtg, ldA, Sg, Pg);
  scan_passB<<<32 * 16, 256, 0, stream>>>(Sg, Pg, inis, Hg);
  scan_passC_mfma<<<32 * NC, 256, 0, stream>>>(xT, bTg, xbc, dtg, ldA, Hg, Dp, yfull);

  gate_norm_kernel<<<ROWS, 256, 0, stream>>>(yfull, zb, nw, yn);
  // GEMM2: M=8192, N=1024 (8 tiles), K=2048 -> 32x8 = 256 blocks
  gemm8p<1><<<32 * 8, 512, 0, stream>>>(yn, woutT, DINNER, 8, HM, nullptr, tb, nullptr, nullptr, nullptr);
  // GEMM3: M=8192, N=1024, K=1024 -> 256 blocks
  gemm8p<2><<<32 * 8, 512, 0, stream>>>(tb, wnlT, HM, 8, HM, out, nullptr, b_nl, x, nullptr);
}

// Round 7
// 388.192 us; speedup vs baseline: 2.7945x; 1.0202x over previous
//
#include <hip/hip_runtime.h>
#include <stdint.h>
#include <stddef.h>

// ---------------- problem dims ----------------
#define BATCH   4
#define SEQLEN  2048
#define HM      1024
#define DINNER  2048
#define NH      8
#define HD      256
#define NS      64
#define CONVD   2176
#define DCONV   16
#define DPROJ   4232
#define ROWS    (BATCH*SEQLEN)  // 8192
#define QC      256             // big-chunk length
#define NC      (SEQLEN/QC)     // 8 big-chunks
#define SC      64              // sub-chunk length (passC)
#define TT      16              // conv timesteps per thread

typedef __attribute__((ext_vector_type(8))) short short8;
typedef __attribute__((ext_vector_type(4))) short short4v;
typedef __attribute__((ext_vector_type(4))) float f32x4;

// ---------------- workspace layout (bytes), peak ~139.5 MiB ----------------
static constexpr size_t O_WOUT   = 0;                    //  4,194,304
static constexpr size_t O_WNL    = 4194304;              //  2,097,152
static constexpr size_t O_DT     = 6291456;              //    262,144
static constexpr size_t O_LDA    = 6553600;              //    262,144
static constexpr size_t O_PG     = 6815744;              //      4,096
static constexpr size_t O_BT     = 6819840;              //  1,048,576
static constexpr size_t O_ZB     = 7868416;              // 33,554,432  bf16 z[8192][2048]
static constexpr size_t O_XBCPRE = 41422848;             // 35,651,584  bf16 [8192][2176]
static constexpr size_t O_SG     = O_XBCPRE;             // 16,777,216  f32 [65536][64]
static constexpr size_t O_HG     = O_XBCPRE + 16777216;  // 16,777,216  f32 [256][16384]
static constexpr size_t O_TB     = O_XBCPRE;             // 16,777,216  bf16 [8192][1024]
static constexpr size_t O_XBC    = 77074432;             // 35,651,584  bf16 [8192][2176]
static constexpr size_t O_YN     = O_XBC;                // 33,554,432  bf16 [8192][2048]
static constexpr size_t O_XTR    = 112726016;            // 33,554,432  bf16 xT[2048][8192]
static constexpr size_t O_XBF    = O_XTR;                // 16,777,216  bf16 [8192][1024]
static constexpr size_t O_WIN    = O_XTR + 16777216;     //  8,912,896  bf16 [4352][1024]
// END = 146,280,448

// ---------------- helpers ----------------
__device__ __forceinline__ short f2bf(float f) {
  union { float f; uint32_t u; } v; v.f = f;
  uint32_t r = v.u + 0x7fffu + ((v.u >> 16) & 1u);
  return (short)(r >> 16);
}

__device__ __forceinline__ float bf2f(short s) {
  union { float f; uint32_t u; } v;
  v.u = ((uint32_t)(uint16_t)s) << 16;
  return v.f;
}

__device__ __forceinline__ void gload_lds16(const void* g, void* l) {
  __builtin_amdgcn_global_load_lds(
      (const __attribute__((address_space(1))) uint32_t*)g,
      (__attribute__((address_space(3))) uint32_t*)l, 16, 0, 0);
}

__device__ __forceinline__ float sigmoidf_fast(float x) {
  return 1.f / (1.f + __expf(-x));
}

// fragment read from a [rows][64-elem] bf16 LDS tile (128B rows, XOR-swizzled)
__device__ __forceinline__ short8 fragr(const char* base, int row, int kbyte) {
  return *(const short8*)(base + row * 128 + (kbyte ^ ((row & 7) << 4)));
}

// ---------------- cast x (row-major, coalesced) ----------------
__global__ __launch_bounds__(256) void cast_x_kernel(const float* __restrict__ x,
                                                     short* __restrict__ xb) {
  int i = blockIdx.x * 256 + threadIdx.x;
  f32x4 v = ((const f32x4*)x)[i];
  short4v o = { f2bf(v[0]), f2bf(v[1]), f2bf(v[2]), f2bf(v[3]) };
  ((short4v*)xb)[i] = o;
}

// ---------------- generic LDS-tiled transpose-cast -------------------------
__global__ __launch_bounds__(256)
void transpose_cast_kernel(const float* __restrict__ W, short* __restrict__ Wt,
                           int srcN, int validN, int Kdim, int nTilesN) {
  __shared__ short lds[64][72];
  int bid = blockIdx.x;
  int k0 = (bid / nTilesN) * 64;
  int n0 = (bid % nTilesN) * 64;
  int tid = threadIdx.x;
  int rr = tid >> 4;
  int cc = (tid & 15) * 4;
#pragma unroll
  for (int pass = 0; pass < 4; ++pass) {
    int k = pass * 16 + rr;
    int gn = n0 + cc;
    f32x4 v = (f32x4)0.f;
    if (gn < validN) v = *(const f32x4*)(W + (size_t)(k0 + k) * srcN + gn);
    uint32_t p0 = (uint32_t)(uint16_t)f2bf(v[0]) | ((uint32_t)(uint16_t)f2bf(v[1]) << 16);
    uint32_t p1 = (uint32_t)(uint16_t)f2bf(v[2]) | ((uint32_t)(uint16_t)f2bf(v[3]) << 16);
    *(uint32_t*)&lds[k][cc] = p0;
    *(uint32_t*)&lds[k][cc + 2] = p1;
  }
  __syncthreads();
  int n = tid >> 2;
  int ks = (tid & 3) * 16;
  short8 a, b;
#pragma unroll
  for (int j = 0; j < 8; ++j) a[j] = lds[ks + j][n];
#pragma unroll
  for (int j = 0; j < 8; ++j) b[j] = lds[ks + 8 + j][n];
  short* dst = Wt + (size_t)(n0 + n) * Kdim + k0 + ks;
  *(short8*)dst = a;
  *(short8*)(dst + 8) = b;
}

// ---------------- dt in f32 (exp-amplified path, exact) ----------------
__global__ __launch_bounds__(256) void dt_kernel(const float* __restrict__ x,
                                                 const float* __restrict__ W_in,
                                                 const float* __restrict__ dt_bias,
                                                 const float* __restrict__ A_log,
                                                 float* __restrict__ dtg,
                                                 float* __restrict__ ldA) {
  int row = blockIdx.x, tid = threadIdx.x;
  float p[NH];
#pragma unroll
  for (int h = 0; h < NH; ++h) p[h] = 0.f;
  for (int k = tid; k < HM; k += 256) {
    float xv = x[(size_t)row * HM + k];
    const float* w = &W_in[(size_t)k * DPROJ + (DPROJ - NH)];
#pragma unroll
    for (int h = 0; h < NH; ++h) p[h] = fmaf(xv, w[h], p[h]);
  }
#pragma unroll
  for (int h = 0; h < NH; ++h)
#pragma unroll
    for (int o = 32; o; o >>= 1) p[h] += __shfl_down(p[h], o);
  __shared__ float red[4][NH];
  int lane = tid & 63, w4 = tid >> 6;
  if (lane == 0)
#pragma unroll
    for (int h = 0; h < NH; ++h) red[w4][h] = p[h];
  __syncthreads();
  if (tid < NH) {
    float s = red[0][tid] + red[1][tid] + red[2][tid] + red[3][tid] + dt_bias[tid];
    float dtv = (s > 20.f) ? s : log1pf(expf(s));
    float A = -expf(A_log[tid]);
    dtg[row * NH + tid] = dtv;
    ldA[row * NH + tid] = dtv * A;
  }
}

// ---------------- 8-wave 256x128 pipelined bf16 GEMM (2-phase/K-tile) ------
// A [M][K] bf16 row-major, B [N][K] bf16 row-major. K % 128 == 0.
// Ring of 3 LDS slots; compute kt from slot kt%3 while staging kt+2 into
// slot (kt+2)%3 (held kt-1, fully consumed -> race-free by construction).
// 2 phases/K-tile, 16 MFMA per barrier-pair, counted vmcnt(6), setprio.
// EPI 1: t=y*rsqrt(1+y^2)->bf16  EPI 2: y+bias+resid->f32  EPI 4: split zb/xbcpre
template <int EPI>
__global__ __launch_bounds__(512)
void gemm8p(const short* __restrict__ A, const short* __restrict__ B,
            int K, int nTilesN, int N_out,
            float* __restrict__ Cf, short* __restrict__ Cb,
            const float* __restrict__ bias, const float* __restrict__ resid,
            short* __restrict__ Cb2) {
  __shared__ alignas(16) char lds[147456];  // 3 slots x 48KB
  const int tid = threadIdx.x;
  int bid = blockIdx.x;
  {  // XCD-chunked swizzle (all grids % 8 == 0)
    int nwg = gridDim.x;
    if ((nwg & 7) == 0) bid = (bid & 7) * (nwg >> 3) + (bid >> 3);
  }
  const int m0 = (bid / nTilesN) * 256;
  const int n0 = (bid % nTilesN) * 128;
  const int lane = tid & 63;
  const int wid = tid >> 6;          // 8 waves
  const int wm = wid >> 1;           // 0..3 -> rows wm*64
  const int wn = wid & 1;            // 0..1 -> cols wn*64
  const int lrow = lane & 15, lk = lane >> 4;
  const int nK = K >> 6;

#define LDSA(s) (lds + (s) * 49152)
#define LDSB(s) (lds + (s) * 49152 + 32768)

#define STAGE_A(s, kt, it) do {                                              \
    int p_ = (it) * 8192 + tid * 16;                                         \
    int row_ = p_ >> 7, c_ = p_ & 127;                                       \
    int sc_ = c_ ^ ((row_ & 7) << 4);                                        \
    gload_lds16((const char*)A + ((size_t)(m0 + row_) * K + (kt) * 64) * 2 + sc_, \
                LDSA(s) + p_);                                               \
  } while (0)
#define STAGE_B(s, kt, it) do {                                              \
    int p_ = (it) * 8192 + tid * 16;                                         \
    int row_ = p_ >> 7, c_ = p_ & 127;                                       \
    int sc_ = c_ ^ ((row_ & 7) << 4);                                        \
    gload_lds16((const char*)B + ((size_t)(n0 + row_) * K + (kt) * 64) * 2 + sc_, \
                LDSB(s) + p_);                                               \
  } while (0)

  f32x4 acc[4][4];
#pragma unroll
  for (int i = 0; i < 4; ++i)
#pragma unroll
    for (int j = 0; j < 4; ++j) acc[i][j] = (f32x4)0.f;

  // prologue: stage kt=0 -> slot0, kt=1 -> slot1; wait kt0 (leave kt1 in flight)
#pragma unroll
  for (int it = 0; it < 4; ++it) STAGE_A(0, 0, it);
#pragma unroll
  for (int it = 0; it < 2; ++it) STAGE_B(0, 0, it);
#pragma unroll
  for (int it = 0; it < 4; ++it) STAGE_A(1, 1, it);
#pragma unroll
  for (int it = 0; it < 2; ++it) STAGE_B(1, 1, it);
  asm volatile("s_waitcnt vmcnt(6)" ::: "memory");
  __builtin_amdgcn_s_barrier();

  for (int kt = 0; kt < nK; ++kt) {
    const int rs = kt % 3;
    const int ss = (kt + 2) % 3;
    const bool st = (kt + 2) < nK;
    const char* Ab = LDSA(rs);
    const char* Bb = LDSB(rs);
    short8 aF[4][2], bF[4][2];

    // ---- phase A: read all A-frags + B(j0,j1); stage A of kt+2 (4 loads)
#pragma unroll
    for (int ii = 0; ii < 4; ++ii)
#pragma unroll
      for (int ks = 0; ks < 2; ++ks)
        aF[ii][ks] = fragr(Ab, wm * 64 + ii * 16 + lrow, ks * 64 + lk * 16);
#pragma unroll
    for (int jj = 0; jj < 2; ++jj)
#pragma unroll
      for (int ks = 0; ks < 2; ++ks)
        bF[jj][ks] = fragr(Bb, wn * 64 + jj * 16 + lrow, ks * 64 + lk * 16);
    if (st) { STAGE_A(ss, kt + 2, 0); STAGE_A(ss, kt + 2, 1); STAGE_A(ss, kt + 2, 2); STAGE_A(ss, kt + 2, 3); }
    __builtin_amdgcn_s_barrier();
    asm volatile("s_waitcnt lgkmcnt(0)" ::: "memory");
    __builtin_amdgcn_s_setprio(1);
#pragma unroll
    for (int ii = 0; ii < 4; ++ii)
#pragma unroll
      for (int jj = 0; jj < 2; ++jj)
#pragma unroll
        for (int ks = 0; ks < 2; ++ks)
          acc[ii][jj] = __builtin_amdgcn_mfma_f32_16x16x32_bf16(aF[ii][ks], bF[jj][ks], acc[ii][jj], 0, 0, 0);
    __builtin_amdgcn_s_setprio(0);
    __builtin_amdgcn_s_barrier();

    // ---- phase B: read B(j2,j3); stage B of kt+2 (2 loads); vmcnt gate
#pragma unroll
    for (int jj = 2; jj < 4; ++jj)
#pragma unroll
      for (int ks = 0; ks < 2; ++ks)
        bF[jj][ks] = fragr(Bb, wn * 64 + jj * 16 + lrow, ks * 64 + lk * 16);
    if (st) { STAGE_B(ss, kt + 2, 0); STAGE_B(ss, kt + 2, 1); }
    __builtin_amdgcn_s_barrier();
    asm volatile("s_waitcnt lgkmcnt(0)" ::: "memory");
    __builtin_amdgcn_s_setprio(1);
#pragma unroll
    for (int ii = 0; ii < 4; ++ii)
#pragma unroll
      for (int jj = 2; jj < 4; ++jj)
#pragma unroll
        for (int ks = 0; ks < 2; ++ks)
          acc[ii][jj] = __builtin_amdgcn_mfma_f32_16x16x32_bf16(aF[ii][ks], bF[jj][ks], acc[ii][jj], 0, 0, 0);
    __builtin_amdgcn_s_setprio(0);
    if (kt >= nK - 2) {
      asm volatile("s_waitcnt vmcnt(0)" ::: "memory");
    } else {
      asm volatile("s_waitcnt vmcnt(6)" ::: "memory");
    }
    __builtin_amdgcn_s_barrier();
  }

  const int row0 = m0 + wm * 64, col0 = n0 + wn * 64;
#pragma unroll
  for (int i = 0; i < 4; ++i)
#pragma unroll
    for (int j = 0; j < 4; ++j)
#pragma unroll
      for (int r = 0; r < 4; ++r) {
        int row = row0 + i * 16 + lk * 4 + r;
        int col = col0 + j * 16 + lrow;
        float v = acc[i][j][r];
        if (EPI == 1) {
          float t = v * rsqrtf(1.f + v * v);
          Cb[(size_t)row * N_out + col] = f2bf(t);
        } else if (EPI == 2) {
          Cf[(size_t)row * N_out + col] = v + bias[col] + resid[(size_t)row * N_out + col];
        } else {  // EPI 4: cols<2048 -> zb; 2048..4223 -> xbcpre
          if (col < DINNER) Cb[(size_t)row * DINNER + col] = f2bf(v);
          else if (col < DINNER + CONVD) Cb2[(size_t)row * CONVD + (col - DINNER)] = f2bf(v);
        }
      }
#undef LDSA
#undef LDSB
#undef STAGE_A
#undef STAGE_B
}

// ---------------- depthwise causal conv16 + SiLU, register-blocked ----------
__global__ __launch_bounds__(256) void conv_silu_kernel(const short* __restrict__ xbcpre,
                                                        const float* __restrict__ cw,
                                                        const float* __restrict__ cbias,
                                                        short* __restrict__ xbc,
                                                        short* __restrict__ xT,
                                                        short* __restrict__ bTg) {
  __shared__ short tld[64][130];   // [t][128 ch + 2 pad]
  int blk = blockIdx.x;            // 17*32*4
  int cg = blk % 17;
  int tg = (blk / 17) % 32;
  int b  = blk / (17 * 32);
  int lane = threadIdx.x & 63;
  int warp = threadIdx.x >> 6;
  int c0 = cg * 128 + lane * 2;
  int tbase = (tg * 4 + warp) * TT;

  const short* inp = xbcpre + (size_t)(b * SEQLEN) * CONVD + c0;
  uint32_t in[TT + DCONV - 1];
#pragma unroll
  for (int j = 0; j < TT + DCONV - 1; ++j) {
    int t = tbase + j - (DCONV - 1);
    in[j] = (t >= 0) ? *(const uint32_t*)(inp + (size_t)t * CONVD) : 0u;
  }
  float w0[DCONV], w1[DCONV];
  const float* wp = cw + (size_t)c0 * DCONV;
#pragma unroll
  for (int k = 0; k < DCONV; ++k) { w0[k] = wp[k]; w1[k] = wp[DCONV + k]; }
  float bb0 = cbias[c0], bb1 = cbias[c0 + 1];

  short* outp = xbc + (size_t)(b * SEQLEN) * CONVD + c0;
#pragma unroll
  for (int tt = 0; tt < TT; ++tt) {
    float a0 = bb0, a1 = bb1;
#pragma unroll
    for (int k = 0; k < DCONV; ++k) {
      uint32_t v = in[tt + k];
      a0 = fmaf(bf2f((short)(v & 0xffffu)), w0[k], a0);
      a1 = fmaf(bf2f((short)(v >> 16)), w1[k], a1);
    }
    a0 = a0 * sigmoidf_fast(a0);
    a1 = a1 * sigmoidf_fast(a1);
    uint32_t o = (uint32_t)(uint16_t)f2bf(a0) | ((uint32_t)(uint16_t)f2bf(a1) << 16);
    *(uint32_t*)(outp + (size_t)(tbase + tt) * CONVD) = o;
    *(uint32_t*)&tld[warp * TT + tt][lane * 2] = o;
  }
  __syncthreads();
  int ch = threadIdx.x & 127;
  int seg = threadIdx.x >> 7;
  int gc = cg * 128 + ch;
  short* dst = nullptr;
  if (gc < DINNER) dst = xT + (size_t)gc * ROWS;
  else if (gc < DINNER + NS) dst = bTg + (size_t)(gc - DINNER) * ROWS;
  if (dst) {
    int tcol = b * SEQLEN + tg * 64 + seg * 32;
    short8 v[4];
#pragma unroll
    for (int q = 0; q < 4; ++q)
#pragma unroll
      for (int j = 0; j < 8; ++j) v[q][j] = tld[seg * 32 + q * 8 + j][ch];
    short8* dp = (short8*)(dst + tcol);
    dp[0] = v[0]; dp[1] = v[1]; dp[2] = v[2]; dp[3] = v[3];
  }
}

// ---------------- scan pass A (MFMA): big-chunk state contribution ----------
__global__ __launch_bounds__(256)
void scan_passA_mfma(const short* __restrict__ xT, const short* __restrict__ bTg,
                     const float* __restrict__ dtg, const float* __restrict__ ldA,
                     float* __restrict__ Sg, float* __restrict__ Pg) {
  __shared__ alignas(16) char Ax[32768];   // [256p][64s]
  __shared__ alignas(16) char Bt[8192];    // [64n][64s]
  __shared__ float aa[QC + 1];
  __shared__ float wdt[QC];
  int blk = blockIdx.x;
  int c8 = blk & 7, bh = blk >> 3;
  int h = bh & 7, b = bh >> 3;
  int tid = threadIdx.x, wave = tid >> 6, lane = tid & 63;
  int lrow = lane & 15, lk = lane >> 4;
  int rowbase = b * SEQLEN + c8 * QC;
  if (tid == 0) {
    float s = 0.f; aa[0] = 0.f;
    for (int t = 0; t < QC; ++t) { s += ldA[(rowbase + t) * NH + h]; aa[t + 1] = s; }
    Pg[blk] = __expf(s);
  }
  __syncthreads();
  float alast = aa[QC];
  wdt[tid] = __expf(alast - aa[tid + 1]) * dtg[(rowbase + tid) * NH + h];

  f32x4 acc[4][4];
#pragma unroll
  for (int i = 0; i < 4; ++i)
#pragma unroll
    for (int j = 0; j < 4; ++j) acc[i][j] = (f32x4)0.f;

  for (int ks = 0; ks < 4; ++ks) {
    int s0 = ks * 64;
#pragma unroll
    for (int it = 0; it < 8; ++it) {
      int p = it * 4096 + tid * 16;
      int row = p >> 7, c = p & 127;
      int sc = c ^ ((row & 7) << 4);
      gload_lds16((const char*)(xT + (size_t)(h * HD + row) * ROWS + rowbase + s0) + sc, Ax + p);
    }
#pragma unroll
    for (int it = 0; it < 2; ++it) {
      int p = it * 4096 + tid * 16;
      int row = p >> 7, c = p & 127;
      int sc = c ^ ((row & 7) << 4);
      gload_lds16((const char*)(bTg + (size_t)row * ROWS + rowbase + s0) + sc, Bt + p);
    }
    asm volatile("s_waitcnt vmcnt(0)" ::: "memory");
    __syncthreads();
    {
      int row = tid;
#pragma unroll
      for (int g = 0; g < 8; ++g) {
        int off = row * 128 + g * 16;
        int sb = s0 + (((g * 16) ^ ((row & 7) << 4)) >> 1);
        short8 v = *(short8*)(Ax + off);
        short8 o;
#pragma unroll
        for (int j = 0; j < 8; ++j) o[j] = f2bf(bf2f(v[j]) * wdt[sb + j]);
        *(short8*)(Ax + off) = o;
      }
    }
    __syncthreads();
#pragma unroll
    for (int kk = 0; kk < 2; ++kk) {
      short8 av[4], bv[4];
#pragma unroll
      for (int i = 0; i < 4; ++i) {
        av[i] = fragr(Ax, wave * 64 + i * 16 + lrow, kk * 64 + lk * 16);
        bv[i] = fragr(Bt, i * 16 + lrow, kk * 64 + lk * 16);
      }
#pragma unroll
      for (int i = 0; i < 4; ++i)
#pragma unroll
        for (int j = 0; j < 4; ++j)
          acc[i][j] = __builtin_amdgcn_mfma_f32_16x16x32_bf16(av[i], bv[j], acc[i][j], 0, 0, 0);
    }
    __syncthreads();
  }
#pragma unroll
  for (int i = 0; i < 4; ++i)
#pragma unroll
    for (int j = 0; j < 4; ++j)
#pragma unroll
      for (int r = 0; r < 4; ++r) {
        int p = wave * 64 + i * 16 + lk * 4 + r;
        int n = j * 16 + lrow;
        Sg[((size_t)blk * 256 + p) * 64 + n] = acc[i][j][r];
      }
}

// ---------------- scan pass B: inter-chunk combine ----------
__global__ __launch_bounds__(256)
void scan_passB(const float* __restrict__ Sg, const float* __restrict__ Pg,
                const float* __restrict__ init, float* __restrict__ Hg) {
  int blk = blockIdx.x;
  int ptile = blk & 15, bh = blk >> 4;
  int h = bh & (NH - 1);
  int tid = threadIdx.x;
  size_t off = (size_t)ptile * 1024 + tid * 4;
  f32x4 hc = *(const f32x4*)(init + (size_t)h * HD * NS + off);
#pragma unroll 1
  for (int c = 0; c < NC; ++c) {
    *(f32x4*)(Hg + (size_t)(bh * NC + c) * 16384 + off) = hc;
    float P = Pg[bh * NC + c];
    f32x4 s = *(const f32x4*)(Sg + (size_t)(bh * NC + c) * 16384 + off);
    hc = P * hc + s;
  }
}

// ---------------- scan pass C (MFMA): chunked y computation ----------------
__global__ __launch_bounds__(256)
void scan_passC_mfma(const short* __restrict__ xT, const short* __restrict__ bTg,
                     const short* __restrict__ xbc,
                     const float* __restrict__ dtg, const float* __restrict__ ldA,
                     const float* __restrict__ Hg, const float* __restrict__ Dp,
                     short* __restrict__ yfull) {
  __shared__ alignas(16) char Xb[32768];   // [256p][64s]
  __shared__ alignas(16) char Hb[32768];   // [256p][64n]
  __shared__ alignas(16) char Bn[8192];    // [64s][64n]
  __shared__ alignas(16) char Cn[8192];    // [64t][64n]
  __shared__ alignas(16) char Bt2[8192];   // [64n][64s]
  __shared__ alignas(16) char Mm[8192];    // [64t][64s]
  __shared__ float aa[QC + 1];
  __shared__ float dts[QC];
  int blk = blockIdx.x;
  int c8 = blk & 7, bh = blk >> 3;
  int h = bh & 7, b = bh >> 3;
  int tid = threadIdx.x, wave = tid >> 6, lane = tid & 63;
  int lrow = lane & 15, lk = lane >> 4;
  int rowbase = b * SEQLEN + c8 * QC;
  if (tid == 0) {
    float s = 0.f; aa[0] = 0.f;
    for (int t = 0; t < QC; ++t) { s += ldA[(rowbase + t) * NH + h]; aa[t + 1] = s; }
  }
  dts[tid] = dtg[(rowbase + tid) * NH + h];
  __syncthreads();
  float Dh = Dp[h];

  f32x4 hcc[4][4];
  const float* hp = Hg + (size_t)blk * 16384;
#pragma unroll
  for (int i = 0; i < 4; ++i)
#pragma unroll
    for (int j = 0; j < 4; ++j)
#pragma unroll
      for (int r = 0; r < 4; ++r)
        hcc[i][j][r] = hp[(size_t)(wave * 64 + i * 16 + lk * 4 + r) * 64 + j * 16 + lrow];

  for (int sc = 0; sc < 4; ++sc) {
    int s0 = sc * SC;
#pragma unroll
    for (int i = 0; i < 4; ++i)
#pragma unroll
      for (int j = 0; j < 4; ++j)
#pragma unroll
        for (int r = 0; r < 4; ++r) {
          int p = wave * 64 + i * 16 + lk * 4 + r;
          int n = j * 16 + lrow;
          *(short*)(Hb + p * 128 + ((n * 2) ^ ((p & 7) << 4))) = f2bf(hcc[i][j][r]);
        }
#pragma unroll
    for (int it = 0; it < 8; ++it) {
      int p = it * 4096 + tid * 16;
      int row = p >> 7, c = p & 127;
      int scz = c ^ ((row & 7) << 4);
      gload_lds16((const char*)(xT + (size_t)(h * HD + row) * ROWS + rowbase + s0) + scz, Xb + p);
    }
#pragma unroll
    for (int it = 0; it < 2; ++it) {
      int p = it * 4096 + tid * 16;
      int row = p >> 7, c = p & 127;
      int scz = c ^ ((row & 7) << 4);
      gload_lds16((const char*)(xbc + (size_t)(rowbase + s0 + row) * CONVD + DINNER) + scz, Bn + p);
      gload_lds16((const char*)(xbc + (size_t)(rowbase + s0 + row) * CONVD + DINNER + NS) + scz, Cn + p);
      gload_lds16((const char*)(bTg + (size_t)row * ROWS + rowbase + s0) + scz, Bt2 + p);
    }
    asm volatile("s_waitcnt vmcnt(0)" ::: "memory");
    __syncthreads();  // S1

    f32x4 gcc[4];
#pragma unroll
    for (int j = 0; j < 4; ++j) gcc[j] = (f32x4)0.f;
#pragma unroll
    for (int kk = 0; kk < 2; ++kk) {
      short8 avc = fragr(Cn, wave * 16 + lrow, kk * 64 + lk * 16);
#pragma unroll
      for (int j = 0; j < 4; ++j) {
        short8 bvb = fragr(Bn, j * 16 + lrow, kk * 64 + lk * 16);
        gcc[j] = __builtin_amdgcn_mfma_f32_16x16x32_bf16(avc, bvb, gcc[j], 0, 0, 0);
      }
    }
#pragma unroll
    for (int j = 0; j < 4; ++j)
#pragma unroll
      for (int r = 0; r < 4; ++r) {
        int t = wave * 16 + lk * 4 + r;
        int s = j * 16 + lrow;
        float val = (s <= t) ? gcc[j][r] * __expf(aa[s0 + t + 1] - aa[s0 + s + 1]) * dts[s0 + s]
                             : 0.f;
        *(short*)(Mm + t * 128 + ((s * 2) ^ ((t & 7) << 4))) = f2bf(val);
      }
#pragma unroll
    for (int pass = 0; pass < 2; ++pass) {
      int t = wave * 16 + (lane >> 3) + pass * 8;
      int g = lane & 7;
      int off = t * 128 + g * 16;
      float fac = __expf(aa[s0 + t + 1] - aa[s0]);
      short8 v = *(short8*)(Cn + off);
      short8 o;
#pragma unroll
      for (int j = 0; j < 8; ++j) o[j] = f2bf(bf2f(v[j]) * fac);
      *(short8*)(Cn + off) = o;
    }
    __syncthreads();  // S2

    f32x4 ycc[4][4];
#pragma unroll
    for (int i = 0; i < 4; ++i)
#pragma unroll
      for (int j = 0; j < 4; ++j) ycc[i][j] = (f32x4)0.f;
#pragma unroll
    for (int kk = 0; kk < 2; ++kk) {
      short8 av[4], bv[4];
#pragma unroll
      for (int i = 0; i < 4; ++i) {
        av[i] = fragr(Mm, i * 16 + lrow, kk * 64 + lk * 16);
        bv[i] = fragr(Xb, wave * 64 + i * 16 + lrow, kk * 64 + lk * 16);
      }
#pragma unroll
      for (int i = 0; i < 4; ++i)
#pragma unroll
        for (int j = 0; j < 4; ++j)
          ycc[i][j] = __builtin_amdgcn_mfma_f32_16x16x32_bf16(av[i], bv[j], ycc[i][j], 0, 0, 0);
    }
#pragma unroll
    for (int kk = 0; kk < 2; ++kk) {
      short8 av[4], bv[4];
#pragma unroll
      for (int i = 0; i < 4; ++i) {
        av[i] = fragr(Cn, i * 16 + lrow, kk * 64 + lk * 16);
        bv[i] = fragr(Hb, wave * 64 + i * 16 + lrow, kk * 64 + lk * 16);
      }
#pragma unroll
      for (int i = 0; i < 4; ++i)
#pragma unroll
        for (int j = 0; j < 4; ++j)
          ycc[i][j] = __builtin_amdgcn_mfma_f32_16x16x32_bf16(av[i], bv[j], ycc[i][j], 0, 0, 0);
    }
#pragma unroll
    for (int i = 0; i < 4; ++i)
#pragma unroll
      for (int j = 0; j < 4; ++j)
#pragma unroll
        for (int r = 0; r < 4; ++r) {
          int t = i * 16 + lk * 4 + r;
          int p = wave * 64 + j * 16 + lrow;
          float xv = bf2f(*(const short*)(Xb + p * 128 + ((t * 2) ^ ((p & 7) << 4))));
          yfull[(size_t)(rowbase + s0 + t) * DINNER + h * HD + p] = f2bf(ycc[i][j][r] + Dh * xv);
        }
    {
      int row = tid;
      float aend = aa[s0 + SC];
#pragma unroll
      for (int g = 0; g < 8; ++g) {
        int off = row * 128 + g * 16;
        int sb = s0 + (((g * 16) ^ ((row & 7) << 4)) >> 1);
        short8 v = *(short8*)(Xb + off);
        short8 o;
#pragma unroll
        for (int j = 0; j < 8; ++j)
          o[j] = f2bf(bf2f(v[j]) * __expf(aend - aa[sb + j + 1]) * dts[sb + j]);
        *(short8*)(Xb + off) = o;
      }
    }
    {
      float Ps = __expf(aa[s0 + SC] - aa[s0]);
#pragma unroll
      for (int i = 0; i < 4; ++i)
#pragma unroll
        for (int j = 0; j < 4; ++j) hcc[i][j] *= Ps;
#pragma unroll
      for (int kk = 0; kk < 2; ++kk) {
        short8 av[4], bv[4];
#pragma unroll
        for (int i = 0; i < 4; ++i) {
          av[i] = fragr(Xb, wave * 64 + i * 16 + lrow, kk * 64 + lk * 16);
          bv[i] = fragr(Bt2, i * 16 + lrow, kk * 64 + lk * 16);
        }
#pragma unroll
        for (int i = 0; i < 4; ++i)
#pragma unroll
          for (int j = 0; j < 4; ++j)
            hcc[i][j] = __builtin_amdgcn_mfma_f32_16x16x32_bf16(av[i], bv[j], hcc[i][j], 0, 0, 0);
      }
    }
    __syncthreads();  // S3
  }
}

// ---------------- gate (silu(z)) + RMSNorm -> bf16 ----------------
__global__ __launch_bounds__(256)
void gate_norm_kernel(const short* __restrict__ yfull, const short* __restrict__ zb,
                      const float* __restrict__ norm_w, short* __restrict__ yn) {
  int row = blockIdx.x, tid = threadIdx.x;
  size_t yb = (size_t)row * DINNER;
  float v[8];
  float ss = 0.f;
#pragma unroll
  for (int g = 0; g < 2; ++g) {
    int cidx = g * 1024 + tid * 4;
    short4v y4 = *(const short4v*)(yfull + yb + cidx);
    short4v z4 = *(const short4v*)(zb + yb + cidx);
#pragma unroll
    for (int j = 0; j < 4; ++j) {
      float z = bf2f(z4[j]);
      float val = bf2f(y4[j]) * z * sigmoidf_fast(z);
      v[g * 4 + j] = val;
      ss = fmaf(val, val, ss);
    }
  }
#pragma unroll
  for (int o = 32; o; o >>= 1) ss += __shfl_down(ss, o);
  __shared__ float red[4];
  if ((tid & 63) == 0) red[tid >> 6] = ss;
  __syncthreads();
  float tot = red[0] + red[1] + red[2] + red[3];
  float scale = rsqrtf(tot * (1.f / (float)DINNER) + 1e-5f);
#pragma unroll
  for (int g = 0; g < 2; ++g) {
    int cidx = g * 1024 + tid * 4;
    short4v o4;
#pragma unroll
    for (int j = 0; j < 4; ++j) o4[j] = f2bf(v[g * 4 + j] * scale * norm_w[cidx + j]);
    *(short4v*)(yn + yb + cidx) = o4;
  }
}

// ---------------- launcher ----------------
extern "C" void kernel_launch(void* const* d_in, const int* in_sizes, int n_in,
                              void* d_out, int out_size, void* d_ws, size_t ws_size,
                              hipStream_t stream) {
  (void)in_sizes; (void)n_in; (void)out_size; (void)ws_size;
  const float* x     = (const float*)d_in[0];
  const float* W_in  = (const float*)d_in[1];
  const float* convw = (const float*)d_in[2];
  const float* convb = (const float*)d_in[3];
  const float* dtb   = (const float*)d_in[4];
  const float* Alog  = (const float*)d_in[5];
  const float* Dp    = (const float*)d_in[6];
  const float* inis  = (const float*)d_in[7];
  const float* nw    = (const float*)d_in[8];
  const float* W_out = (const float*)d_in[9];
  const float* W_nl  = (const float*)d_in[10];
  const float* b_nl  = (const float*)d_in[11];
  float* out = (float*)d_out;
  char* ws = (char*)d_ws;

  short* woutT  = (short*)(ws + O_WOUT);
  short* wnlT   = (short*)(ws + O_WNL);
  float* dtg    = (float*)(ws + O_DT);
  float* ldA    = (float*)(ws + O_LDA);
  float* Pg     = (float*)(ws + O_PG);
  short* bTg    = (short*)(ws + O_BT);
  short* zb     = (short*)(ws + O_ZB);
  short* xbcpre = (short*)(ws + O_XBCPRE);
  float* Sg     = (float*)(ws + O_SG);
  float* Hg     = (float*)(ws + O_HG);
  short* tb     = (short*)(ws + O_TB);
  short* xbc    = (short*)(ws + O_XBC);
  short* yn     = (short*)(ws + O_YN);
  short* xT     = (short*)(ws + O_XTR);
  short* xbf    = (short*)(ws + O_XBF);
  short* winT   = (short*)(ws + O_WIN);
  short* yfull  = (short*)d_out;

  cast_x_kernel<<<8192, 256, 0, stream>>>(x, xbf);
  transpose_cast_kernel<<<16 * 68, 256, 0, stream>>>(W_in, winT, DPROJ, DPROJ, HM, 68);
  transpose_cast_kernel<<<32 * 16, 256, 0, stream>>>(W_out, woutT, HM, HM, DINNER, 16);
  transpose_cast_kernel<<<16 * 16, 256, 0, stream>>>(W_nl, wnlT, HM, HM, HM, 16);
  dt_kernel<<<ROWS, 256, 0, stream>>>(x, W_in, dtb, Alog, dtg, ldA);

  // GEMM1: M=8192, N=4352 (34 tiles of 128), K=1024 -> 32x34 = 1088 blocks
  gemm8p<4><<<32 * 34, 512, 0, stream>>>(xbf, winT, HM, 34, 0, nullptr, zb, nullptr, nullptr, xbcpre);
  conv_silu_kernel<<<17 * 32 * 4, 256, 0, stream>>>(xbcpre, convw, convb, xbc, xT, bTg);

  scan_passA_mfma<<<32 * NC, 256, 0, stream>>>(xT, bTg, dtg, ldA, Sg, Pg);
  scan_passB<<<32 * 16, 256, 0, stream>>>(Sg, Pg, inis, Hg);
  scan_passC_mfma<<<32 * NC, 256, 0, stream>>>(xT, bTg, xbc, dtg, ldA, Hg, Dp, yfull);

  gate_norm_kernel<<<ROWS, 256, 0, stream>>>(yfull, zb, nw, yn);
  // GEMM2: M=8192, N=1024 (8 tiles), K=2048 -> 32x8 = 256 blocks
  gemm8p<1><<<32 * 8, 512, 0, stream>>>(yn, woutT, DINNER, 8, HM, nullptr, tb, nullptr, nullptr, nullptr);
  // GEMM3: M=8192, N=1024, K=1024 -> 256 blocks
  gemm8p<2><<<32 * 8, 512, 0, stream>>>(tb, wnlT, HM, 8, HM, out, nullptr, b_nl, x, nullptr);
}